// Round 1
// baseline (3889.941 us; speedup 1.0000x reference)
//
#include <hip/hip_runtime.h>
#include <hip/hip_bf16.h>
#include <cstddef>

// ---------------- generic fp32 GEMM: C[M,N] = A[M,K] @ B[K,N] (+bias) ----------------
#define GBM 64
#define GBN 64
#define GBK 32

__global__ __launch_bounds__(256) void gemm_f32(
    const float* __restrict__ A, const float* __restrict__ B,
    const float* __restrict__ bias, float* __restrict__ C,
    int M, int N, int K)
{
    __shared__ float As[GBK][GBM + 4];   // transposed: As[k][m]
    __shared__ float Bs[GBK][GBN + 4];
    const int tid = threadIdx.x;
    const int tx = tid & 15, ty = tid >> 4;
    const int bm0 = blockIdx.y * GBM, bn0 = blockIdx.x * GBN;

    float acc[4][4] = {};

    for (int k0 = 0; k0 < K; k0 += GBK) {
        __syncthreads();
        // load A tile: 64 rows x 32 cols = 512 float4, 2 per thread (transposed store)
        #pragma unroll
        for (int p = 0; p < 2; ++p) {
            int l = tid + p * 256;
            int row = l >> 3, c4 = (l & 7) * 4;
            float4 a4 = *(const float4*)(A + (size_t)(bm0 + row) * K + k0 + c4);
            As[c4 + 0][row] = a4.x; As[c4 + 1][row] = a4.y;
            As[c4 + 2][row] = a4.z; As[c4 + 3][row] = a4.w;
        }
        // load B tile: 32 rows x 64 cols
        #pragma unroll
        for (int p = 0; p < 2; ++p) {
            int l = tid + p * 256;
            int row = l >> 4, c4 = (l & 15) * 4;
            *(float4*)&Bs[row][c4] = *(const float4*)(B + (size_t)(k0 + row) * N + bn0 + c4);
        }
        __syncthreads();
        #pragma unroll
        for (int kk = 0; kk < GBK; ++kk) {
            const float4 av = *(const float4*)&As[kk][ty * 4];
            const float4 bv = *(const float4*)&Bs[kk][tx * 4];
            acc[0][0] += av.x * bv.x; acc[0][1] += av.x * bv.y; acc[0][2] += av.x * bv.z; acc[0][3] += av.x * bv.w;
            acc[1][0] += av.y * bv.x; acc[1][1] += av.y * bv.y; acc[1][2] += av.y * bv.z; acc[1][3] += av.y * bv.w;
            acc[2][0] += av.z * bv.x; acc[2][1] += av.z * bv.y; acc[2][2] += av.z * bv.z; acc[2][3] += av.z * bv.w;
            acc[3][0] += av.w * bv.x; acc[3][1] += av.w * bv.y; acc[3][2] += av.w * bv.z; acc[3][3] += av.w * bv.w;
        }
    }

    const int row0 = bm0 + ty * 4;
    const int col0 = bn0 + tx * 4;
    float4 bb = {0.f, 0.f, 0.f, 0.f};
    if (bias) bb = *(const float4*)(bias + col0);
    #pragma unroll
    for (int mi = 0; mi < 4; ++mi) {
        float4 o;
        o.x = acc[mi][0] + bb.x; o.y = acc[mi][1] + bb.y;
        o.z = acc[mi][2] + bb.z; o.w = acc[mi][3] + bb.w;
        *(float4*)(C + (size_t)(row0 + mi) * N + col0) = o;
    }
}

// ---------------- build kv_input = concat([cmem, mem, x], dim 1) ----------------
__global__ __launch_bounds__(256) void concat_kv(
    const float* __restrict__ x, const float* __restrict__ mem,
    const float* __restrict__ cmem, float* __restrict__ out)
{
    int rowg = blockIdx.x;               // 0..9215
    int b = rowg / 2304, rr = rowg % 2304;
    const float* src = (rr < 256)  ? cmem + ((size_t)b * 256 + rr) * 1024
                     : (rr < 1280) ? mem  + ((size_t)b * 1024 + (rr - 256)) * 1024
                                   : x    + ((size_t)b * 1024 + (rr - 1280)) * 1024;
    float4 v = ((const float4*)src)[threadIdx.x];
    ((float4*)(out + (size_t)rowg * 1024))[threadIdx.x] = v;
}

// ---------------- conv_w[o,i,r] -> W2[r*1024+i, o] ----------------
__global__ __launch_bounds__(256) void transpose_w2(
    const float* __restrict__ cw, float* __restrict__ w2)
{
    int kk = blockIdx.y;                       // 0..4095
    int o = blockIdx.x * 256 + threadIdx.x;    // 0..1023
    int i = kk & 1023, r = kk >> 10;
    w2[(size_t)kk * 1024 + o] = cw[(size_t)o * 4096 + i * 4 + r];
}

// ---------------- main attention: out(b,i,e) ----------------
// scores(i,j) = 0.125*(q.k[j] + q.pe[1023+j-i]) for j<=i+1280, else masked
__global__ __launch_bounds__(256) void attn_main(
    const float* __restrict__ qb,    // (4,1024,1024)
    const float* __restrict__ kvb,   // (4,2304,2048) k|v
    const float* __restrict__ pe,    // (16,2304,64)
    float* __restrict__ outb)        // (4,1024,1024)
{
    __shared__ float qs[16][64];
    __shared__ float ks[64][65];
    __shared__ float vs[64][68];
    __shared__ float pes[79][65];
    __shared__ float ps[16][65];

    const int bh = blockIdx.y;
    const int b = bh >> 4, h = bh & 15;
    const int i0 = blockIdx.x * 16;
    const int tid = threadIdx.x;
    const int r = tid >> 4, c = tid & 15;
    const int i = i0 + r;
    const int ilim = i + 1280;

    {   // load q tile (one float4 per thread)
        int row = tid >> 4, c4 = (tid & 15) * 4;
        *(float4*)&qs[row][c4] =
            *(const float4*)(qb + ((size_t)(b * 1024 + i0 + row)) * 1024 + h * 64 + c4);
    }

    float m = -1e30f, lsum = 0.f;
    float o0 = 0.f, o1 = 0.f, o2 = 0.f, o3 = 0.f;

    const int jlimit = i0 + 15 + 1280;
    for (int j0 = 0; j0 <= jlimit; j0 += 64) {
        __syncthreads();
        // load k/v tile
        #pragma unroll
        for (int p = 0; p < 4; ++p) {
            int l = tid + p * 256;
            int row = l >> 4, c4 = (l & 15) * 4;
            const float* src = kvb + ((size_t)(b * 2304 + j0 + row)) * 2048 + h * 64 + c4;
            float4 k4 = *(const float4*)src;
            ks[row][c4 + 0] = k4.x; ks[row][c4 + 1] = k4.y;
            ks[row][c4 + 2] = k4.z; ks[row][c4 + 3] = k4.w;
            *(float4*)&vs[row][c4] = *(const float4*)(src + 1024);
        }
        // load pe tile rows jj0 .. jj0+78
        const int jj0 = 1023 + j0 - i0 - 15;
        #pragma unroll
        for (int p = 0; p < 5; ++p) {
            int l = tid + p * 256;                 // 0..1279
            int row = l >> 4, c4 = (l & 15) * 4;   // row 0..79
            if (row < 79) {
                int jj = jj0 + row; if (jj > 2303) jj = 2303;
                float4 v4 = *(const float4*)(pe + ((size_t)(h * 2304 + jj)) * 64 + c4);
                pes[row][c4 + 0] = v4.x; pes[row][c4 + 1] = v4.y;
                pes[row][c4 + 2] = v4.z; pes[row][c4 + 3] = v4.w;
            }
        }
        __syncthreads();

        // scores: thread (r,c) -> j = j0 + c + 16s
        float s0 = 0, s1 = 0, s2 = 0, s3 = 0;
        float p0 = 0, p1 = 0, p2 = 0, p3 = 0;
        const int pr0 = c - r + 15;
        #pragma unroll 8
        for (int kk = 0; kk < 64; ++kk) {
            float qv = qs[r][kk];
            s0 += qv * ks[c][kk];      s1 += qv * ks[c + 16][kk];
            s2 += qv * ks[c + 32][kk]; s3 += qv * ks[c + 48][kk];
            p0 += qv * pes[pr0][kk];      p1 += qv * pes[pr0 + 16][kk];
            p2 += qv * pes[pr0 + 32][kk]; p3 += qv * pes[pr0 + 48][kk];
        }
        float sv0 = (j0 + c      <= ilim) ? (s0 + p0) * 0.125f : -1e30f;
        float sv1 = (j0 + c + 16 <= ilim) ? (s1 + p1) * 0.125f : -1e30f;
        float sv2 = (j0 + c + 32 <= ilim) ? (s2 + p2) * 0.125f : -1e30f;
        float sv3 = (j0 + c + 48 <= ilim) ? (s3 + p3) * 0.125f : -1e30f;

        // online softmax across the 16 lanes of this row
        float tmax = fmaxf(fmaxf(sv0, sv1), fmaxf(sv2, sv3));
        #pragma unroll
        for (int mk = 1; mk < 16; mk <<= 1) tmax = fmaxf(tmax, __shfl_xor(tmax, mk));
        float mnew = fmaxf(m, tmax);
        float corr = __expf(m - mnew);
        float pv0 = __expf(sv0 - mnew), pv1 = __expf(sv1 - mnew);
        float pv2 = __expf(sv2 - mnew), pv3 = __expf(sv3 - mnew);
        float psum = pv0 + pv1 + pv2 + pv3;
        #pragma unroll
        for (int mk = 1; mk < 16; mk <<= 1) psum += __shfl_xor(psum, mk);
        lsum = lsum * corr + psum;
        m = mnew;
        o0 *= corr; o1 *= corr; o2 *= corr; o3 *= corr;
        ps[r][c] = pv0; ps[r][c + 16] = pv1; ps[r][c + 32] = pv2; ps[r][c + 48] = pv3;
        __syncthreads();

        // PV: thread (r,c) accumulates out cols c*4..c*4+3
        #pragma unroll 8
        for (int jl = 0; jl < 64; ++jl) {
            float p = ps[r][jl];
            float4 vv = *(const float4*)&vs[jl][c * 4];
            o0 += p * vv.x; o1 += p * vv.y; o2 += p * vv.z; o3 += p * vv.w;
        }
    }
    float inv = 1.f / lsum;
    float4 res = {o0 * inv, o1 * inv, o2 * inv, o3 * inv};
    *(float4*)(outb + ((size_t)(b * 1024 + i)) * 1024 + h * 64 + c * 4) = res;
}

// ---------------- aux loss: sum over (full_attn(q,omk,omv)-full_attn(q,ck,cv))^2 ----------------
__global__ __launch_bounds__(256) void attn_aux(
    const float* __restrict__ qb, const float* __restrict__ kvb,
    const float* __restrict__ ckcv, float* __restrict__ acc)
{
    __shared__ float qs[16][64];
    __shared__ float ks[64][65];
    __shared__ float vs[64][68];
    __shared__ float ps[16][65];
    __shared__ float red[4];

    const int bh = blockIdx.y;
    const int b = bh >> 4, h = bh & 15;
    const int i0 = blockIdx.x * 16;
    const int tid = threadIdx.x;
    const int r = tid >> 4, c = tid & 15;

    {
        int row = tid >> 4, c4 = (tid & 15) * 4;
        *(float4*)&qs[row][c4] =
            *(const float4*)(qb + ((size_t)(b * 1024 + i0 + row)) * 1024 + h * 64 + c4);
    }

    float oph[2][4];
    for (int phase = 0; phase < 2; ++phase) {
        const float* kvsrc = (phase == 0)
            ? kvb + ((size_t)(b * 2304 + 256)) * 2048 + h * 64
            : ckcv + ((size_t)(b * 256)) * 2048 + h * 64;
        const int jlen = (phase == 0) ? 1024 : 256;

        float m = -1e30f, lsum = 0.f;
        float o0 = 0.f, o1 = 0.f, o2 = 0.f, o3 = 0.f;
        for (int j0 = 0; j0 < jlen; j0 += 64) {
            __syncthreads();
            #pragma unroll
            for (int p = 0; p < 4; ++p) {
                int l = tid + p * 256;
                int row = l >> 4, c4 = (l & 15) * 4;
                const float* src = kvsrc + (size_t)(j0 + row) * 2048 + c4;
                float4 k4 = *(const float4*)src;
                ks[row][c4 + 0] = k4.x; ks[row][c4 + 1] = k4.y;
                ks[row][c4 + 2] = k4.z; ks[row][c4 + 3] = k4.w;
                *(float4*)&vs[row][c4] = *(const float4*)(src + 1024);
            }
            __syncthreads();
            float s0 = 0, s1 = 0, s2 = 0, s3 = 0;
            #pragma unroll 8
            for (int kk = 0; kk < 64; ++kk) {
                float qv = qs[r][kk];
                s0 += qv * ks[c][kk];      s1 += qv * ks[c + 16][kk];
                s2 += qv * ks[c + 32][kk]; s3 += qv * ks[c + 48][kk];
            }
            s0 *= 0.125f; s1 *= 0.125f; s2 *= 0.125f; s3 *= 0.125f;
            float tmax = fmaxf(fmaxf(s0, s1), fmaxf(s2, s3));
            #pragma unroll
            for (int mk = 1; mk < 16; mk <<= 1) tmax = fmaxf(tmax, __shfl_xor(tmax, mk));
            float mnew = fmaxf(m, tmax);
            float corr = __expf(m - mnew);
            float pv0 = __expf(s0 - mnew), pv1 = __expf(s1 - mnew);
            float pv2 = __expf(s2 - mnew), pv3 = __expf(s3 - mnew);
            float psum = pv0 + pv1 + pv2 + pv3;
            #pragma unroll
            for (int mk = 1; mk < 16; mk <<= 1) psum += __shfl_xor(psum, mk);
            lsum = lsum * corr + psum;
            m = mnew;
            o0 *= corr; o1 *= corr; o2 *= corr; o3 *= corr;
            ps[r][c] = pv0; ps[r][c + 16] = pv1; ps[r][c + 32] = pv2; ps[r][c + 48] = pv3;
            __syncthreads();
            #pragma unroll 8
            for (int jl = 0; jl < 64; ++jl) {
                float p = ps[r][jl];
                float4 vv = *(const float4*)&vs[jl][c * 4];
                o0 += p * vv.x; o1 += p * vv.y; o2 += p * vv.z; o3 += p * vv.w;
            }
        }
        float inv = 1.f / lsum;
        oph[phase][0] = o0 * inv; oph[phase][1] = o1 * inv;
        oph[phase][2] = o2 * inv; oph[phase][3] = o3 * inv;
    }

    float local = 0.f;
    #pragma unroll
    for (int d = 0; d < 4; ++d) {
        float dd = oph[0][d] - oph[1][d];
        local += dd * dd;
    }
    #pragma unroll
    for (int mk = 1; mk < 64; mk <<= 1) local += __shfl_xor(local, mk);
    if ((tid & 63) == 0) red[tid >> 6] = local;
    __syncthreads();
    if (tid == 0) atomicAdd(acc, red[0] + red[1] + red[2] + red[3]);
}

__global__ void finish_aux(const float* __restrict__ acc, float* __restrict__ out)
{
    out[0] = acc[0] * (1.0f / 4194304.0f);
}

// ---------------- launch ----------------
extern "C" void kernel_launch(void* const* d_in, const int* in_sizes, int n_in,
                              void* d_out, int out_size, void* d_ws, size_t ws_size,
                              hipStream_t stream)
{
    const float* x     = (const float*)d_in[0];
    const float* mem   = (const float*)d_in[1];
    const float* cmem  = (const float*)d_in[2];
    const float* pos   = (const float*)d_in[3];
    // d_in[4] = input_mask (all true) unused
    const float* Wq    = (const float*)d_in[5];
    const float* Wkv   = (const float*)d_in[6];
    const float* Wout  = (const float*)d_in[7];
    const float* bout  = (const float*)d_in[8];
    const float* convw = (const float*)d_in[9];
    const float* convb = (const float*)d_in[10];

    float* out      = (float*)d_out;
    float* logits   = out;                 // 4*1024*1024
    float* new_mem  = out + 4194304;       // 4*1024*1024
    float* new_cmem = out + 8388608;       // 4*256*1024
    float* aux_out  = out + 9437184;       // 1

    float* ws       = (float*)d_ws;
    float* kv_buf   = ws;                   // 4*2304*2048 = 18874368
    float* q_buf    = kv_buf + 18874368;    // 4194304
    float* scratch2 = q_buf + 4194304;      // 9437184 floats, reused region
    float* kv_input = scratch2;             // steps 1-2
    float* W2       = scratch2;             // steps 4-5 (after kv GEMM)
    float* attn_out = scratch2;             // steps 7-8 (after W2 dead)
    float* ckcv     = scratch2 + 4194304;   // 2097152
    float* acc      = ws + 32505856;        // 1 float

    // independent copy: new_mem = x
    hipMemcpyAsync(new_mem, x, (size_t)4194304 * sizeof(float),
                   hipMemcpyDeviceToDevice, stream);

    concat_kv<<<9216, 256, 0, stream>>>(x, mem, cmem, kv_input);
    gemm_f32<<<dim3(32, 144), 256, 0, stream>>>(kv_input, Wkv, nullptr, kv_buf, 9216, 2048, 1024);
    gemm_f32<<<dim3(16, 64), 256, 0, stream>>>(x, Wq, nullptr, q_buf, 4096, 1024, 1024);
    transpose_w2<<<dim3(4, 4096), 256, 0, stream>>>(convw, W2);
    // compressed -> new_cmem (output buffer doubles as GEMM input below)
    gemm_f32<<<dim3(16, 16), 256, 0, stream>>>(mem, W2, convb, new_cmem, 1024, 1024, 4096);
    gemm_f32<<<dim3(32, 16), 256, 0, stream>>>(new_cmem, Wkv, nullptr, ckcv, 1024, 2048, 1024);
    attn_main<<<dim3(64, 64), 256, 0, stream>>>(q_buf, kv_buf, pos, attn_out);
    gemm_f32<<<dim3(16, 64), 256, 0, stream>>>(attn_out, Wout, bout, logits, 4096, 1024, 1024);

    hipMemsetAsync(acc, 0, sizeof(float), stream);
    attn_aux<<<dim3(64, 64), 256, 0, stream>>>(q_buf, kv_buf, ckcv, acc);
    finish_aux<<<1, 1, 0, stream>>>(acc, aux_out);
}

// Round 2
// 678.318 us; speedup vs baseline: 5.7347x; 5.7347x over previous
//
#include <hip/hip_runtime.h>
#include <hip/hip_bf16.h>
#include <cstddef>

typedef unsigned short u16;
typedef __attribute__((ext_vector_type(8))) short bf16x8;
typedef __attribute__((ext_vector_type(4))) float f32x4;

__device__ __forceinline__ u16 f2b(float f) {
    unsigned u = __builtin_bit_cast(unsigned, f);
    unsigned r = (u + 0x7FFF + ((u >> 16) & 1)) >> 16;
    return (u16)r;
}

__device__ __forceinline__ void gload_lds16(const void* g, void* l) {
    __builtin_amdgcn_global_load_lds(
        (const __attribute__((address_space(1))) unsigned int*)g,
        (__attribute__((address_space(3))) unsigned int*)l, 16, 0, 0);
}

__device__ __forceinline__ bf16x8 mfma_bf16(bf16x8 a, bf16x8 b); // unused decl guard

// ---------------- elementwise fp32 -> bf16 ----------------
__global__ __launch_bounds__(256) void cvt_bf16(const float* __restrict__ in,
                                                u16* __restrict__ out, int n4)
{
    int i = blockIdx.x * 256 + threadIdx.x;
    if (i >= n4) return;
    float4 v = ((const float4*)in)[i];
    union { u16 s[4]; uint2 u; } pk;
    pk.s[0] = f2b(v.x); pk.s[1] = f2b(v.y); pk.s[2] = f2b(v.z); pk.s[3] = f2b(v.w);
    ((uint2*)out)[i] = pk.u;
}

// ---------------- kv_input concat (bf16) ----------------
__global__ __launch_bounds__(256) void concat_bf16(
    const float* __restrict__ x, const float* __restrict__ mem,
    const float* __restrict__ cmem, u16* __restrict__ out)
{
    int rowg = blockIdx.x;               // 0..9215
    int b = rowg / 2304, rr = rowg % 2304;
    const float* src = (rr < 256)  ? cmem + ((size_t)b * 256 + rr) * 1024
                     : (rr < 1280) ? mem  + ((size_t)b * 1024 + (rr - 256)) * 1024
                                   : x    + ((size_t)b * 1024 + (rr - 1280)) * 1024;
    float4 v = ((const float4*)src)[threadIdx.x];
    union { u16 s[4]; uint2 u; } pk;
    pk.s[0] = f2b(v.x); pk.s[1] = f2b(v.y); pk.s[2] = f2b(v.z); pk.s[3] = f2b(v.w);
    ((uint2*)(out + (size_t)rowg * 1024))[threadIdx.x] = pk.u;
}

// ---------------- transpose fp32 [K][N] -> bf16 [N][K] ----------------
__global__ __launch_bounds__(256) void transpose_bf16(
    const float* __restrict__ in, u16* __restrict__ out, int K, int N)
{
    __shared__ float t[32][33];
    int k0 = blockIdx.y * 32, n0 = blockIdx.x * 32;
    int tx = threadIdx.x & 31, ty = threadIdx.x >> 5;
    #pragma unroll
    for (int p = 0; p < 4; ++p)
        t[ty + 8 * p][tx] = in[(size_t)(k0 + ty + 8 * p) * N + n0 + tx];
    __syncthreads();
    #pragma unroll
    for (int p = 0; p < 4; ++p)
        out[(size_t)(n0 + ty + 8 * p) * K + k0 + tx] = f2b(t[tx][ty + 8 * p]);
}

// ---------------- conv_w[o,i,r] -> W2t[o][r*1024+i] bf16 ----------------
__global__ __launch_bounds__(256) void w2t_bf16(const float* __restrict__ cw,
                                                u16* __restrict__ out)
{
    size_t idx = (size_t)blockIdx.x * 256 + threadIdx.x;  // 1024*4096
    int o = (int)(idx >> 12), k = (int)(idx & 4095);
    out[idx] = f2b(cw[(size_t)o * 4096 + (k & 1023) * 4 + (k >> 10)]);
}

// ---------------- bf16 MFMA GEMM: C[M,N] = A[M,K] @ Bt[N,K]^T (+bias) ----------------
__global__ __launch_bounds__(256) void gemm_bf16(
    const u16* __restrict__ A, const u16* __restrict__ Bt,
    const float* __restrict__ bias, float* __restrict__ Cf,
    u16* __restrict__ Cb, int M, int N, int K)
{
    __shared__ u16 Al[128 * 32];
    __shared__ u16 Bl[128 * 32];
    const int tid = threadIdx.x, w = tid >> 6, lane = tid & 63;
    const int lr = lane & 15, lg = lane >> 4;
    const int bm0 = blockIdx.y * 128, bn0 = blockIdx.x * 128;
    const int wr = (w >> 1) * 64, wc = (w & 1) * 64;

    f32x4 acc[4][4];
    const f32x4 z = {0.f, 0.f, 0.f, 0.f};
    #pragma unroll
    for (int mb = 0; mb < 4; ++mb)
        #pragma unroll
        for (int nb = 0; nb < 4; ++nb) acc[mb][nb] = z;

    for (int k0 = 0; k0 < K; k0 += 32) {
        __syncthreads();
        #pragma unroll
        for (int q = 0; q < 2; ++q) {
            int chunk = w * 2 + q;
            int row = chunk * 16 + (lane >> 2);
            int sg = (lane & 3) * 8;
            gload_lds16(A + (size_t)(bm0 + row) * K + k0 + sg, &Al[chunk * 512]);
            gload_lds16(Bt + (size_t)(bn0 + row) * K + k0 + sg, &Bl[chunk * 512]);
        }
        __syncthreads();
        bf16x8 af[4], bf[4];
        #pragma unroll
        for (int mb = 0; mb < 4; ++mb)
            af[mb] = *(const bf16x8*)&Al[(wr + mb * 16 + lr) * 32 + lg * 8];
        #pragma unroll
        for (int nb = 0; nb < 4; ++nb)
            bf[nb] = *(const bf16x8*)&Bl[(wc + nb * 16 + lr) * 32 + lg * 8];
        #pragma unroll
        for (int mb = 0; mb < 4; ++mb)
            #pragma unroll
            for (int nb = 0; nb < 4; ++nb)
                acc[mb][nb] = __builtin_amdgcn_mfma_f32_16x16x32_bf16(
                    af[mb], bf[nb], acc[mb][nb], 0, 0, 0);
    }

    #pragma unroll
    for (int mb = 0; mb < 4; ++mb)
        #pragma unroll
        for (int nb = 0; nb < 4; ++nb)
            #pragma unroll
            for (int jr = 0; jr < 4; ++jr) {
                int row = bm0 + wr + mb * 16 + lg * 4 + jr;
                int col = bn0 + wc + nb * 16 + lr;
                float v = acc[mb][nb][jr] + (bias ? bias[col] : 0.f);
                if (Cf) Cf[(size_t)row * N + col] = v;
                if (Cb) Cb[(size_t)row * N + col] = f2b(v);
            }
}

// ---------------- main attention (MFMA) ----------------
__global__ __launch_bounds__(256) void attn_main_mfma(
    const u16* __restrict__ qb,    // (4,1024,1024) bf16
    const u16* __restrict__ kvb,   // (4,2304,2048) bf16 k|v
    const u16* __restrict__ peb,   // (16,2304,64) bf16
    u16* __restrict__ outb)        // (4,1024,1024) bf16
{
    __shared__ u16 kls[64 * 64];
    __shared__ u16 vls[64 * 64];      // transposed [d][j], swizzled
    __shared__ u16 pels[128 * 64];
    __shared__ float qpls[4][16][80];
    __shared__ u16 pls[4][16 * 72];

    const int tid = threadIdx.x;
    const int w = tid >> 6, lane = tid & 63;
    const int lr = lane & 15, lg = lane >> 4;
    const int bh = blockIdx.y, b = bh >> 4, h = bh & 15;
    const int i0 = blockIdx.x * 64;
    const int iw = i0 + 16 * w;

    bf16x8 qf[2];
    #pragma unroll
    for (int ks = 0; ks < 2; ++ks)
        qf[ks] = *(const bf16x8*)(qb + ((size_t)(b * 1024 + iw + lr)) * 1024
                                  + h * 64 + ks * 32 + lg * 8);

    const f32x4 z = {0.f, 0.f, 0.f, 0.f};
    f32x4 od[4];
    float mloc[4], lloc[4];
    #pragma unroll
    for (int nb = 0; nb < 4; ++nb) od[nb] = z;
    #pragma unroll
    for (int jr = 0; jr < 4; ++jr) { mloc[jr] = -1e30f; lloc[jr] = 0.f; }

    const int nt = ((i0 + 1343) >> 6) + 1;
    for (int t = 0; t < nt; ++t) {
        const int j0 = t * 64;
        // ---- stage K, V(transposed), PE ----
        #pragma unroll
        for (int p = 0; p < 2; ++p) {
            int idx = tid + p * 256;
            int j = idx >> 3, sg = idx & 7;
            const u16* g = kvb + ((size_t)(b * 2304 + j0 + j)) * 2048 + h * 64 + sg * 8;
            uint4 kd = *(const uint4*)g;
            uint4 vd = *(const uint4*)(g + 1024);
            *(uint4*)&kls[j * 64 + ((sg ^ (j & 7)) * 8)] = kd;
            const u16* vp = (const u16*)&vd;
            #pragma unroll
            for (int u2 = 0; u2 < 8; ++u2) {
                int d = sg * 8 + u2;
                vls[d * 64 + (((j >> 3) ^ (d & 7)) * 8) + (j & 7)] = vp[u2];
            }
        }
        const int jb = 960 + j0 - i0;
        #pragma unroll
        for (int p = 0; p < 4; ++p) {
            int idx = tid + p * 256;
            int rr = idx >> 3, sg = idx & 7;
            int jj = jb + rr; jj = jj > 2303 ? 2303 : jj;
            uint4 pd = *(const uint4*)(peb + ((size_t)(h * 2304 + jj)) * 64 + sg * 8);
            *(uint4*)&pels[rr * 64 + ((sg ^ (rr & 7)) * 8)] = pd;
        }
        __syncthreads();

        // ---- QK & QP MFMA ----
        f32x4 qk[4], qp[5];
        #pragma unroll
        for (int nb = 0; nb < 4; ++nb) qk[nb] = z;
        #pragma unroll
        for (int nb = 0; nb < 5; ++nb) qp[nb] = z;
        #pragma unroll
        for (int ks = 0; ks < 2; ++ks) {
            #pragma unroll
            for (int nb = 0; nb < 4; ++nb) {
                int row = nb * 16 + lr;
                bf16x8 kb = *(const bf16x8*)&kls[row * 64 + (((4 * ks + lg) ^ (row & 7)) * 8)];
                qk[nb] = __builtin_amdgcn_mfma_f32_16x16x32_bf16(qf[ks], kb, qk[nb], 0, 0, 0);
            }
            #pragma unroll
            for (int nb = 0; nb < 5; ++nb) {
                int row = 48 - 16 * w + nb * 16 + lr;
                bf16x8 pb = *(const bf16x8*)&pels[row * 64 + (((4 * ks + lg) ^ (row & 7)) * 8)];
                qp[nb] = __builtin_amdgcn_mfma_f32_16x16x32_bf16(qf[ks], pb, qp[nb], 0, 0, 0);
            }
        }
        #pragma unroll
        for (int nb = 0; nb < 5; ++nb)
            #pragma unroll
            for (int jr = 0; jr < 4; ++jr)
                qpls[w][lg * 4 + jr][nb * 16 + lr] = qp[nb][jr];

        // ---- mask + online softmax (per q-row = 16 lanes x 4 frags) ----
        #pragma unroll
        for (int jr = 0; jr < 4; ++jr) {
            int r = lg * 4 + jr;
            int ia = iw + r;
            float s[4];
            #pragma unroll
            for (int nb = 0; nb < 4; ++nb) {
                int cc = nb * 16 + lr;
                float v = (qk[nb][jr] + qpls[w][r][cc - r + 15]) * 0.125f;
                s[nb] = (j0 + cc <= ia + 1280) ? v : -1e30f;
            }
            float tm = fmaxf(fmaxf(s[0], s[1]), fmaxf(s[2], s[3]));
            #pragma unroll
            for (int mk = 1; mk < 16; mk <<= 1) tm = fmaxf(tm, __shfl_xor(tm, mk));
            float mn = fmaxf(mloc[jr], tm);
            float corr = __expf(mloc[jr] - mn);
            mloc[jr] = mn;
            float ps = 0.f;
            #pragma unroll
            for (int nb = 0; nb < 4; ++nb) {
                float p = __expf(s[nb] - mn);
                ps += p;
                pls[w][r * 72 + nb * 16 + lr] = f2b(p);
            }
            #pragma unroll
            for (int mk = 1; mk < 16; mk <<= 1) ps += __shfl_xor(ps, mk);
            lloc[jr] = lloc[jr] * corr + ps;
            od[0][jr] *= corr; od[1][jr] *= corr; od[2][jr] *= corr; od[3][jr] *= corr;
        }

        // ---- PV MFMA ----
        #pragma unroll
        for (int ks = 0; ks < 2; ++ks) {
            bf16x8 pa = *(const bf16x8*)&pls[w][lr * 72 + ks * 32 + lg * 8];
            #pragma unroll
            for (int nb = 0; nb < 4; ++nb) {
                int d = nb * 16 + lr;
                bf16x8 vb = *(const bf16x8*)&vls[d * 64 + (((4 * ks + lg) ^ (d & 7)) * 8)];
                od[nb] = __builtin_amdgcn_mfma_f32_16x16x32_bf16(pa, vb, od[nb], 0, 0, 0);
            }
        }
        __syncthreads();
    }

    #pragma unroll
    for (int jr = 0; jr < 4; ++jr) {
        float inv = 1.f / lloc[jr];
        int ia = iw + lg * 4 + jr;
        #pragma unroll
        for (int nb = 0; nb < 4; ++nb)
            outb[((size_t)(b * 1024 + ia)) * 1024 + h * 64 + nb * 16 + lr] =
                f2b(od[nb][jr] * inv);
    }
}

// ---------------- aux attention (MFMA, two phases, squared diff) ----------------
__global__ __launch_bounds__(256) void attn_aux_mfma(
    const u16* __restrict__ qb, const u16* __restrict__ kvb,
    const u16* __restrict__ ckcv, float* __restrict__ acc)
{
    __shared__ u16 kls[64 * 64];
    __shared__ u16 vls[64 * 64];
    __shared__ u16 pls[4][16 * 72];
    __shared__ float red[4];

    const int tid = threadIdx.x;
    const int w = tid >> 6, lane = tid & 63;
    const int lr = lane & 15, lg = lane >> 4;
    const int bh = blockIdx.y, b = bh >> 4, h = bh & 15;
    const int i0 = blockIdx.x * 64;
    const int iw = i0 + 16 * w;

    bf16x8 qf[2];
    #pragma unroll
    for (int ks = 0; ks < 2; ++ks)
        qf[ks] = *(const bf16x8*)(qb + ((size_t)(b * 1024 + iw + lr)) * 1024
                                  + h * 64 + ks * 32 + lg * 8);

    const f32x4 z = {0.f, 0.f, 0.f, 0.f};
    float o0s[4][4];
    float local = 0.f;

    for (int ph = 0; ph < 2; ++ph) {
        const u16* base = (ph == 0)
            ? kvb  + ((size_t)(b * 2304 + 256)) * 2048 + h * 64
            : ckcv + ((size_t)(b * 256)) * 2048 + h * 64;
        const int ntile = (ph == 0) ? 16 : 4;

        f32x4 od[4];
        float mloc[4], lloc[4];
        #pragma unroll
        for (int nb = 0; nb < 4; ++nb) od[nb] = z;
        #pragma unroll
        for (int jr = 0; jr < 4; ++jr) { mloc[jr] = -1e30f; lloc[jr] = 0.f; }

        for (int t = 0; t < ntile; ++t) {
            const int j0 = t * 64;
            #pragma unroll
            for (int p = 0; p < 2; ++p) {
                int idx = tid + p * 256;
                int j = idx >> 3, sg = idx & 7;
                const u16* g = base + (size_t)(j0 + j) * 2048 + sg * 8;
                uint4 kd = *(const uint4*)g;
                uint4 vd = *(const uint4*)(g + 1024);
                *(uint4*)&kls[j * 64 + ((sg ^ (j & 7)) * 8)] = kd;
                const u16* vp = (const u16*)&vd;
                #pragma unroll
                for (int u2 = 0; u2 < 8; ++u2) {
                    int d = sg * 8 + u2;
                    vls[d * 64 + (((j >> 3) ^ (d & 7)) * 8) + (j & 7)] = vp[u2];
                }
            }
            __syncthreads();

            f32x4 qk[4];
            #pragma unroll
            for (int nb = 0; nb < 4; ++nb) qk[nb] = z;
            #pragma unroll
            for (int ks = 0; ks < 2; ++ks)
                #pragma unroll
                for (int nb = 0; nb < 4; ++nb) {
                    int row = nb * 16 + lr;
                    bf16x8 kb = *(const bf16x8*)&kls[row * 64 + (((4 * ks + lg) ^ (row & 7)) * 8)];
                    qk[nb] = __builtin_amdgcn_mfma_f32_16x16x32_bf16(qf[ks], kb, qk[nb], 0, 0, 0);
                }

            #pragma unroll
            for (int jr = 0; jr < 4; ++jr) {
                int r = lg * 4 + jr;
                float s[4];
                #pragma unroll
                for (int nb = 0; nb < 4; ++nb) s[nb] = qk[nb][jr] * 0.125f;
                float tm = fmaxf(fmaxf(s[0], s[1]), fmaxf(s[2], s[3]));
                #pragma unroll
                for (int mk = 1; mk < 16; mk <<= 1) tm = fmaxf(tm, __shfl_xor(tm, mk));
                float mn = fmaxf(mloc[jr], tm);
                float corr = __expf(mloc[jr] - mn);
                mloc[jr] = mn;
                float ps = 0.f;
                #pragma unroll
                for (int nb = 0; nb < 4; ++nb) {
                    float p = __expf(s[nb] - mn);
                    ps += p;
                    pls[w][r * 72 + nb * 16 + lr] = f2b(p);
                }
                #pragma unroll
                for (int mk = 1; mk < 16; mk <<= 1) ps += __shfl_xor(ps, mk);
                lloc[jr] = lloc[jr] * corr + ps;
                od[0][jr] *= corr; od[1][jr] *= corr; od[2][jr] *= corr; od[3][jr] *= corr;
            }

            #pragma unroll
            for (int ks = 0; ks < 2; ++ks) {
                bf16x8 pa = *(const bf16x8*)&pls[w][lr * 72 + ks * 32 + lg * 8];
                #pragma unroll
                for (int nb = 0; nb < 4; ++nb) {
                    int d = nb * 16 + lr;
                    bf16x8 vb = *(const bf16x8*)&vls[d * 64 + (((4 * ks + lg) ^ (d & 7)) * 8)];
                    od[nb] = __builtin_amdgcn_mfma_f32_16x16x32_bf16(pa, vb, od[nb], 0, 0, 0);
                }
            }
            __syncthreads();
        }

        if (ph == 0) {
            #pragma unroll
            for (int jr = 0; jr < 4; ++jr) {
                float inv = 1.f / lloc[jr];
                #pragma unroll
                for (int nb = 0; nb < 4; ++nb) o0s[nb][jr] = od[nb][jr] * inv;
            }
        } else {
            #pragma unroll
            for (int jr = 0; jr < 4; ++jr) {
                float inv = 1.f / lloc[jr];
                #pragma unroll
                for (int nb = 0; nb < 4; ++nb) {
                    float d = o0s[nb][jr] - od[nb][jr] * inv;
                    local += d * d;
                }
            }
        }
    }

    #pragma unroll
    for (int mk = 1; mk < 64; mk <<= 1) local += __shfl_xor(local, mk);
    if (lane == 0) red[w] = local;
    __syncthreads();
    if (tid == 0) atomicAdd(acc, red[0] + red[1] + red[2] + red[3]);
}

__global__ void finish_aux(const float* __restrict__ acc, float* __restrict__ out)
{
    out[0] = acc[0] * (1.0f / 4194304.0f);
}

// ---------------- launch ----------------
extern "C" void kernel_launch(void* const* d_in, const int* in_sizes, int n_in,
                              void* d_out, int out_size, void* d_ws, size_t ws_size,
                              hipStream_t stream)
{
    const float* x     = (const float*)d_in[0];
    const float* mem   = (const float*)d_in[1];
    const float* cmem  = (const float*)d_in[2];
    const float* pos   = (const float*)d_in[3];
    const float* Wq    = (const float*)d_in[5];
    const float* Wkv   = (const float*)d_in[6];
    const float* Wout  = (const float*)d_in[7];
    const float* bout  = (const float*)d_in[8];
    const float* convw = (const float*)d_in[9];
    const float* convb = (const float*)d_in[10];

    float* out      = (float*)d_out;
    float* logits   = out;
    float* new_mem  = out + 4194304;
    float* new_cmem = out + 8388608;
    float* aux_out  = out + 9437184;

    char* p = (char*)d_ws;
    u16* kvb   = (u16*)p; p += (size_t)9216 * 2048 * 2;
    u16* qb    = (u16*)p; p += (size_t)4096 * 1024 * 2;
    u16* kvin  = (u16*)p; p += (size_t)9216 * 1024 * 2;
    u16* wkvt  = (u16*)p; p += (size_t)2048 * 1024 * 2;
    u16* wqt   = (u16*)p; p += (size_t)1024 * 1024 * 2;
    u16* woutt = (u16*)p; p += (size_t)1024 * 1024 * 2;
    u16* w2t   = (u16*)p; p += (size_t)1024 * 4096 * 2;
    u16* peb   = (u16*)p; p += (size_t)16 * 2304 * 64 * 2;
    u16* xb    = (u16*)p; p += (size_t)4096 * 1024 * 2;
    u16* memb  = (u16*)p; p += (size_t)4096 * 1024 * 2;
    u16* cmpb  = (u16*)p; p += (size_t)1024 * 1024 * 2;
    u16* ckcvb = (u16*)p; p += (size_t)1024 * 2048 * 2;
    u16* aob   = (u16*)p; p += (size_t)4096 * 1024 * 2;
    float* acc = (float*)p;

    hipMemcpyAsync(new_mem, x, (size_t)4194304 * sizeof(float),
                   hipMemcpyDeviceToDevice, stream);

    cvt_bf16<<<4096, 256, 0, stream>>>(x, xb, 1048576);
    cvt_bf16<<<4096, 256, 0, stream>>>(mem, memb, 1048576);
    cvt_bf16<<<2304, 256, 0, stream>>>(pos, peb, 589824);
    concat_bf16<<<9216, 256, 0, stream>>>(x, mem, cmem, kvin);
    transpose_bf16<<<dim3(64, 32), 256, 0, stream>>>(Wkv, wkvt, 1024, 2048);
    transpose_bf16<<<dim3(32, 32), 256, 0, stream>>>(Wq, wqt, 1024, 1024);
    transpose_bf16<<<dim3(32, 32), 256, 0, stream>>>(Wout, woutt, 1024, 1024);
    w2t_bf16<<<16384, 256, 0, stream>>>(convw, w2t);

    gemm_bf16<<<dim3(16, 72), 256, 0, stream>>>(kvin, wkvt, nullptr, nullptr, kvb, 9216, 2048, 1024);
    gemm_bf16<<<dim3(8, 32), 256, 0, stream>>>(xb, wqt, nullptr, nullptr, qb, 4096, 1024, 1024);
    gemm_bf16<<<dim3(8, 8), 256, 0, stream>>>(memb, w2t, convb, new_cmem, cmpb, 1024, 1024, 4096);
    gemm_bf16<<<dim3(16, 8), 256, 0, stream>>>(cmpb, wkvt, nullptr, nullptr, ckcvb, 1024, 2048, 1024);

    attn_main_mfma<<<dim3(16, 64), 256, 0, stream>>>(qb, kvb, peb, aob);
    gemm_bf16<<<dim3(8, 32), 256, 0, stream>>>(aob, woutt, bout, logits, nullptr, 4096, 1024, 1024);

    hipMemsetAsync(acc, 0, sizeof(float), stream);
    attn_aux_mfma<<<dim3(16, 64), 256, 0, stream>>>(qb, kvb, ckcvb, acc);
    finish_aux<<<1, 1, 0, stream>>>(acc, aux_out);
}

// Round 3
// 561.154 us; speedup vs baseline: 6.9320x; 1.2088x over previous
//
#include <hip/hip_runtime.h>
#include <hip/hip_bf16.h>
#include <cstddef>

typedef unsigned short u16;
typedef __attribute__((ext_vector_type(8))) short bf16x8;
typedef __attribute__((ext_vector_type(4))) float f32x4;

__device__ __forceinline__ u16 f2b(float f) {
    unsigned u = __builtin_bit_cast(unsigned, f);
    unsigned r = (u + 0x7FFF + ((u >> 16) & 1)) >> 16;
    return (u16)r;
}

__device__ __forceinline__ void gload_lds16(const void* g, void* l) {
    __builtin_amdgcn_global_load_lds(
        (const __attribute__((address_space(1))) unsigned int*)g,
        (__attribute__((address_space(3))) unsigned int*)l, 16, 0, 0);
}

// ---------------- elementwise fp32 -> bf16 ----------------
__global__ __launch_bounds__(256) void cvt_bf16(const float* __restrict__ in,
                                                u16* __restrict__ out, int n4)
{
    int i = blockIdx.x * 256 + threadIdx.x;
    if (i >= n4) return;
    float4 v = ((const float4*)in)[i];
    union { u16 s[4]; uint2 u; } pk;
    pk.s[0] = f2b(v.x); pk.s[1] = f2b(v.y); pk.s[2] = f2b(v.z); pk.s[3] = f2b(v.w);
    ((uint2*)out)[i] = pk.u;
}

// ---------------- kv_input concat (bf16) ----------------
__global__ __launch_bounds__(256) void concat_bf16(
    const float* __restrict__ x, const float* __restrict__ mem,
    const float* __restrict__ cmem, u16* __restrict__ out)
{
    int rowg = blockIdx.x;               // 0..9215
    int b = rowg / 2304, rr = rowg % 2304;
    const float* src = (rr < 256)  ? cmem + ((size_t)b * 256 + rr) * 1024
                     : (rr < 1280) ? mem  + ((size_t)b * 1024 + (rr - 256)) * 1024
                                   : x    + ((size_t)b * 1024 + (rr - 1280)) * 1024;
    float4 v = ((const float4*)src)[threadIdx.x];
    union { u16 s[4]; uint2 u; } pk;
    pk.s[0] = f2b(v.x); pk.s[1] = f2b(v.y); pk.s[2] = f2b(v.z); pk.s[3] = f2b(v.w);
    ((uint2*)(out + (size_t)rowg * 1024))[threadIdx.x] = pk.u;
}

// ---------------- transpose fp32 [K][N] -> bf16 [N][K] ----------------
__global__ __launch_bounds__(256) void transpose_bf16(
    const float* __restrict__ in, u16* __restrict__ out, int K, int N)
{
    __shared__ float t[32][33];
    int k0 = blockIdx.y * 32, n0 = blockIdx.x * 32;
    int tx = threadIdx.x & 31, ty = threadIdx.x >> 5;
    #pragma unroll
    for (int p = 0; p < 4; ++p)
        t[ty + 8 * p][tx] = in[(size_t)(k0 + ty + 8 * p) * N + n0 + tx];
    __syncthreads();
    #pragma unroll
    for (int p = 0; p < 4; ++p)
        out[(size_t)(n0 + ty + 8 * p) * K + k0 + tx] = f2b(t[tx][ty + 8 * p]);
}

// ---------------- conv_w[o,i,r] -> W2t[o][r*1024+i] bf16 ----------------
__global__ __launch_bounds__(256) void w2t_bf16(const float* __restrict__ cw,
                                                u16* __restrict__ out)
{
    size_t idx = (size_t)blockIdx.x * 256 + threadIdx.x;  // 1024*4096
    int o = (int)(idx >> 12), k = (int)(idx & 4095);
    out[idx] = f2b(cw[(size_t)o * 4096 + (k & 1023) * 4 + (k >> 10)]);
}

// ---------------- V half of [rows][2048] -> Vt[(bh*64+d)][rows] ----------------
__global__ __launch_bounds__(256) void transpose_v(
    const u16* __restrict__ src, int R, u16* __restrict__ dst)
{
    __shared__ u16 t[64 * 65];
    int bh = blockIdx.y, b = bh >> 4, h = bh & 15;
    int j0 = blockIdx.x * 64;
    int tid = threadIdx.x;
    #pragma unroll
    for (int p = 0; p < 2; ++p) {
        int idx = tid + p * 256;
        int j = idx >> 3, c = idx & 7;
        uint4 v = *(const uint4*)(src + ((size_t)(b * R + j0 + j)) * 2048 + 1024 + h * 64 + c * 8);
        const u16* vv = (const u16*)&v;
        #pragma unroll
        for (int u2 = 0; u2 < 8; ++u2) t[j * 65 + c * 8 + u2] = vv[u2];
    }
    __syncthreads();
    #pragma unroll
    for (int p = 0; p < 2; ++p) {
        int idx = tid + p * 256;
        int jc = idx & 7, d = idx >> 3;
        union { u16 s[8]; uint4 u; } pk;
        #pragma unroll
        for (int u2 = 0; u2 < 8; ++u2) pk.s[u2] = t[(jc * 8 + u2) * 65 + d];
        *(uint4*)(dst + ((size_t)(bh * 64 + d)) * (size_t)R + j0 + jc * 8) = pk.u;
    }
}

// ---------------- bf16 MFMA GEMM: C[M,N] = A[M,K] @ Bt[N,K]^T (+bias) ----------------
__global__ __launch_bounds__(256) void gemm_bf16(
    const u16* __restrict__ A, const u16* __restrict__ Bt,
    const float* __restrict__ bias, float* __restrict__ Cf,
    u16* __restrict__ Cb, int M, int N, int K)
{
    __shared__ u16 Al[128 * 32];
    __shared__ u16 Bl[128 * 32];
    const int tid = threadIdx.x, w = tid >> 6, lane = tid & 63;
    const int lr = lane & 15, lg = lane >> 4;
    const int bm0 = blockIdx.y * 128, bn0 = blockIdx.x * 128;
    const int wr = (w >> 1) * 64, wc = (w & 1) * 64;

    f32x4 acc[4][4];
    const f32x4 z = {0.f, 0.f, 0.f, 0.f};
    #pragma unroll
    for (int mb = 0; mb < 4; ++mb)
        #pragma unroll
        for (int nb = 0; nb < 4; ++nb) acc[mb][nb] = z;

    for (int k0 = 0; k0 < K; k0 += 32) {
        __syncthreads();
        #pragma unroll
        for (int q = 0; q < 2; ++q) {
            int chunk = w * 2 + q;
            int row = chunk * 16 + (lane >> 2);
            int sg = (lane & 3) * 8;
            gload_lds16(A + (size_t)(bm0 + row) * K + k0 + sg, &Al[chunk * 512]);
            gload_lds16(Bt + (size_t)(bn0 + row) * K + k0 + sg, &Bl[chunk * 512]);
        }
        __syncthreads();
        bf16x8 af[4], bf[4];
        #pragma unroll
        for (int mb = 0; mb < 4; ++mb)
            af[mb] = *(const bf16x8*)&Al[(wr + mb * 16 + lr) * 32 + lg * 8];
        #pragma unroll
        for (int nb = 0; nb < 4; ++nb)
            bf[nb] = *(const bf16x8*)&Bl[(wc + nb * 16 + lr) * 32 + lg * 8];
        #pragma unroll
        for (int mb = 0; mb < 4; ++mb)
            #pragma unroll
            for (int nb = 0; nb < 4; ++nb)
                acc[mb][nb] = __builtin_amdgcn_mfma_f32_16x16x32_bf16(
                    af[mb], bf[nb], acc[mb][nb], 0, 0, 0);
    }

    #pragma unroll
    for (int mb = 0; mb < 4; ++mb)
        #pragma unroll
        for (int nb = 0; nb < 4; ++nb)
            #pragma unroll
            for (int jr = 0; jr < 4; ++jr) {
                int row = bm0 + wr + mb * 16 + lg * 4 + jr;
                int col = bn0 + wc + nb * 16 + lr;
                float v = acc[mb][nb][jr] + (bias ? bias[col] : 0.f);
                if (Cf) Cf[(size_t)row * N + col] = v;
                if (Cb) Cb[(size_t)row * N + col] = f2b(v);
            }
}

// ---------------- main attention (MFMA, dbuf K/V, PE ring, defer-max) ----------------
__global__ __launch_bounds__(256) void attn_main_mfma(
    const u16* __restrict__ qb,    // (4,1024,1024) bf16
    const u16* __restrict__ kvb,   // (4,2304,2048) bf16 k|v
    const u16* __restrict__ vt,    // (64bh*64d, 2304) bf16  V^T
    const u16* __restrict__ peb,   // (16,2304,64) bf16
    u16* __restrict__ outb)        // (4,1024,1024) bf16
{
    __shared__ u16 kbuf[2][64 * 64];
    __shared__ u16 vbuf[2][64 * 64];   // [d][j-chunks] swizzled
    __shared__ u16 pering[128 * 64];
    __shared__ u16 pls[4][16 * 72];
    __shared__ float qpls[4][16 * 83];

    const int tid = threadIdx.x;
    const int w = tid >> 6, lane = tid & 63;
    const int lr = lane & 15, lg = lane >> 4;
    const int rl = lane >> 3, cch = lane & 7;
    const int bh = blockIdx.y, b = bh >> 4, h = bh & 15;
    const int i0 = blockIdx.x * 64;
    const int iw = i0 + 16 * w;
    const int jb0 = 960 - i0;

    bf16x8 qf[2];
    #pragma unroll
    for (int ks = 0; ks < 2; ++ks)
        qf[ks] = *(const bf16x8*)(qb + ((size_t)(b * 1024 + iw + lr)) * 1024
                                  + h * 64 + ks * 32 + lg * 8);

    const f32x4 z = {0.f, 0.f, 0.f, 0.f};
    f32x4 od[4];
    float mloc[4], lloc[4];
    #pragma unroll
    for (int nb = 0; nb < 4; ++nb) od[nb] = z;
    #pragma unroll
    for (int jr = 0; jr < 4; ++jr) { mloc[jr] = -1e30f; lloc[jr] = 0.f; }

    // ---- prologue: tile 0 K/V + full 128-row PE band ----
    #pragma unroll
    for (int q = 0; q < 2; ++q) {
        int row = 16 * w + 8 * q + rl;
        gload_lds16(kvb + ((size_t)(b * 2304 + row)) * 2048 + h * 64 + ((cch ^ rl) * 8),
                    &kbuf[0][(16 * w + 8 * q) * 64]);
        gload_lds16(vt + ((size_t)(bh * 64 + row)) * 2304 + ((cch ^ rl) * 8),
                    &vbuf[0][(16 * w + 8 * q) * 64]);
    }
    #pragma unroll
    for (int q = 0; q < 4; ++q) {
        int a = jb0 + 32 * w + 8 * q + rl;
        int srow = a > 2303 ? 2303 : a;
        gload_lds16(peb + ((size_t)(h * 2304 + srow)) * 64 + ((cch ^ rl) * 8),
                    &pering[((jb0 + 32 * w + 8 * q) & 127) * 64]);
    }
    __syncthreads();

    int cur = 0;
    const int nt = ((i0 + 1343) >> 6) + 1;
    for (int t = 0; t < nt; ++t) {
        const int j0 = t * 64;
        const int jb = jb0 + j0;
        const bool more = (t + 1 < nt);

        if (more) {   // K/V staging for next tile (no hazard; overlaps whole tile)
            const int j0n = j0 + 64;
            #pragma unroll
            for (int q = 0; q < 2; ++q) {
                int row = 16 * w + 8 * q + rl;
                gload_lds16(kvb + ((size_t)(b * 2304 + j0n + row)) * 2048 + h * 64 + ((cch ^ rl) * 8),
                            &kbuf[cur ^ 1][(16 * w + 8 * q) * 64]);
                gload_lds16(vt + ((size_t)(bh * 64 + row)) * 2304 + j0n + ((cch ^ rl) * 8),
                            &vbuf[cur ^ 1][(16 * w + 8 * q) * 64]);
            }
        }

        // ---- QK & QP MFMA ----
        f32x4 qk[4], qp[5];
        #pragma unroll
        for (int nb = 0; nb < 4; ++nb) qk[nb] = z;
        #pragma unroll
        for (int f = 0; f < 5; ++f) qp[f] = z;
        #pragma unroll
        for (int ks = 0; ks < 2; ++ks) {
            #pragma unroll
            for (int nb = 0; nb < 4; ++nb) {
                int row = nb * 16 + lr;
                bf16x8 kb = *(const bf16x8*)&kbuf[cur][row * 64 + (((4 * ks + lg) ^ (row & 7)) * 8)];
                qk[nb] = __builtin_amdgcn_mfma_f32_16x16x32_bf16(qf[ks], kb, qk[nb], 0, 0, 0);
            }
            #pragma unroll
            for (int f = 0; f < 5; ++f) {
                int rel = 48 - 16 * w + f * 16 + lr;
                int slot = (jb + rel) & 127;
                bf16x8 pb = *(const bf16x8*)&pering[slot * 64 + (((4 * ks + lg) ^ (slot & 7)) * 8)];
                qp[f] = __builtin_amdgcn_mfma_f32_16x16x32_bf16(qf[ks], pb, qp[f], 0, 0, 0);
            }
        }

        __builtin_amdgcn_s_barrier();   // raw: all waves' PE reads complete (no vm drain)

        if (more) {   // PE ring: stage the 64 new rows for next tile
            const int A0 = jb + 128;
            #pragma unroll
            for (int q = 0; q < 2; ++q) {
                int a = A0 + 16 * w + 8 * q + rl;
                int srow = a > 2303 ? 2303 : a;
                gload_lds16(peb + ((size_t)(h * 2304 + srow)) * 64 + ((cch ^ rl) * 8),
                            &pering[((A0 + 16 * w + 8 * q) & 127) * 64]);
            }
        }

        // ---- spill qp to LDS for diagonal gather ----
        #pragma unroll
        for (int f = 0; f < 5; ++f)
            #pragma unroll
            for (int jr = 0; jr < 4; ++jr)
                qpls[w][(lg * 4 + jr) * 83 + f * 16 + lr] = qp[f][jr];

        // ---- mask + defer-max online softmax ----
        #pragma unroll
        for (int jr = 0; jr < 4; ++jr) {
            const int r = lg * 4 + jr;
            const int ia = iw + r;
            float s[4];
            #pragma unroll
            for (int nb = 0; nb < 4; ++nb) {
                int cc = nb * 16 + lr;
                float v = (qk[nb][jr] + qpls[w][r * 82 + cc + 15]) * 0.125f;
                s[nb] = (j0 + cc <= ia + 1280) ? v : -1e30f;
            }
            float lm = fmaxf(fmaxf(s[0], s[1]), fmaxf(s[2], s[3]));
            if (__any(lm > mloc[jr] + 8.f)) {
                float tm = lm;
                #pragma unroll
                for (int mk = 1; mk < 16; mk <<= 1) tm = fmaxf(tm, __shfl_xor(tm, mk));
                float mn = fmaxf(mloc[jr], tm);
                float corr = __expf(mloc[jr] - mn);
                mloc[jr] = mn; lloc[jr] *= corr;
                od[0][jr] *= corr; od[1][jr] *= corr; od[2][jr] *= corr; od[3][jr] *= corr;
            }
            float ps = 0.f;
            #pragma unroll
            for (int nb = 0; nb < 4; ++nb) {
                float p = __expf(s[nb] - mloc[jr]);
                ps += p;
                pls[w][r * 72 + nb * 16 + lr] = f2b(p);
            }
            lloc[jr] += ps;
        }

        // ---- PV MFMA ----
        #pragma unroll
        for (int ks = 0; ks < 2; ++ks) {
            bf16x8 pa = *(const bf16x8*)&pls[w][lr * 72 + ks * 32 + lg * 8];
            #pragma unroll
            for (int nb = 0; nb < 4; ++nb) {
                int d = nb * 16 + lr;
                bf16x8 vb = *(const bf16x8*)&vbuf[cur][d * 64 + (((4 * ks + lg) ^ (d & 7)) * 8)];
                od[nb] = __builtin_amdgcn_mfma_f32_16x16x32_bf16(pa, vb, od[nb], 0, 0, 0);
            }
        }
        __syncthreads();   // drains staging vmem + all LDS reads
        cur ^= 1;
    }

    #pragma unroll
    for (int jr = 0; jr < 4; ++jr) {
        #pragma unroll
        for (int mk = 1; mk < 16; mk <<= 1) lloc[jr] += __shfl_xor(lloc[jr], mk);
        float inv = 1.f / lloc[jr];
        int ia = iw + lg * 4 + jr;
        #pragma unroll
        for (int nb = 0; nb < 4; ++nb)
            outb[((size_t)(b * 1024 + ia)) * 1024 + h * 64 + nb * 16 + lr] =
                f2b(od[nb][jr] * inv);
    }
}

// ---------------- aux attention (MFMA, dbuf, defer-max, squared diff) ----------------
__global__ __launch_bounds__(256) void attn_aux_mfma(
    const u16* __restrict__ qb, const u16* __restrict__ kvb,
    const u16* __restrict__ vt, const u16* __restrict__ ckcv,
    const u16* __restrict__ cvt, float* __restrict__ acc)
{
    __shared__ u16 kbuf[2][64 * 64];
    __shared__ u16 vbuf[2][64 * 64];
    __shared__ u16 pls[4][16 * 72];
    __shared__ float red[4];

    const int tid = threadIdx.x;
    const int w = tid >> 6, lane = tid & 63;
    const int lr = lane & 15, lg = lane >> 4;
    const int rl = lane >> 3, cch = lane & 7;
    const int bh = blockIdx.y, b = bh >> 4, h = bh & 15;
    const int i0 = blockIdx.x * 64;
    const int iw = i0 + 16 * w;

    bf16x8 qf[2];
    #pragma unroll
    for (int ks = 0; ks < 2; ++ks)
        qf[ks] = *(const bf16x8*)(qb + ((size_t)(b * 1024 + iw + lr)) * 1024
                                  + h * 64 + ks * 32 + lg * 8);

    const f32x4 z = {0.f, 0.f, 0.f, 0.f};
    float o0s[4][4];
    float local = 0.f;

    for (int ph = 0; ph < 2; ++ph) {
        const u16* kbase = ph ? (ckcv + ((size_t)(b * 256)) * 2048 + h * 64)
                              : (kvb + ((size_t)(b * 2304 + 256)) * 2048 + h * 64);
        const u16* vbase = ph ? (cvt + ((size_t)(bh * 64)) * 256)
                              : (vt + ((size_t)(bh * 64)) * 2304 + 256);
        const int vstr = ph ? 256 : 2304;
        const int ntile = ph ? 4 : 16;

        #pragma unroll
        for (int q = 0; q < 2; ++q) {
            int row = 16 * w + 8 * q + rl;
            gload_lds16(kbase + (size_t)row * 2048 + ((cch ^ rl) * 8),
                        &kbuf[0][(16 * w + 8 * q) * 64]);
            gload_lds16(vbase + (size_t)row * vstr + ((cch ^ rl) * 8),
                        &vbuf[0][(16 * w + 8 * q) * 64]);
        }
        __syncthreads();

        int cur = 0;
        f32x4 od[4];
        float mloc[4], lloc[4];
        #pragma unroll
        for (int nb = 0; nb < 4; ++nb) od[nb] = z;
        #pragma unroll
        for (int jr = 0; jr < 4; ++jr) { mloc[jr] = -1e30f; lloc[jr] = 0.f; }

        for (int t = 0; t < ntile; ++t) {
            const bool more = (t + 1 < ntile);
            if (more) {
                const int j0n = (t + 1) * 64;
                #pragma unroll
                for (int q = 0; q < 2; ++q) {
                    int row = 16 * w + 8 * q + rl;
                    gload_lds16(kbase + (size_t)(j0n + row) * 2048 + ((cch ^ rl) * 8),
                                &kbuf[cur ^ 1][(16 * w + 8 * q) * 64]);
                    gload_lds16(vbase + (size_t)row * vstr + j0n + ((cch ^ rl) * 8),
                                &vbuf[cur ^ 1][(16 * w + 8 * q) * 64]);
                }
            }

            f32x4 qk[4];
            #pragma unroll
            for (int nb = 0; nb < 4; ++nb) qk[nb] = z;
            #pragma unroll
            for (int ks = 0; ks < 2; ++ks)
                #pragma unroll
                for (int nb = 0; nb < 4; ++nb) {
                    int row = nb * 16 + lr;
                    bf16x8 kb = *(const bf16x8*)&kbuf[cur][row * 64 + (((4 * ks + lg) ^ (row & 7)) * 8)];
                    qk[nb] = __builtin_amdgcn_mfma_f32_16x16x32_bf16(qf[ks], kb, qk[nb], 0, 0, 0);
                }

            #pragma unroll
            for (int jr = 0; jr < 4; ++jr) {
                const int r = lg * 4 + jr;
                float s[4];
                #pragma unroll
                for (int nb = 0; nb < 4; ++nb) s[nb] = qk[nb][jr] * 0.125f;
                float lm = fmaxf(fmaxf(s[0], s[1]), fmaxf(s[2], s[3]));
                if (__any(lm > mloc[jr] + 8.f)) {
                    float tm = lm;
                    #pragma unroll
                    for (int mk = 1; mk < 16; mk <<= 1) tm = fmaxf(tm, __shfl_xor(tm, mk));
                    float mn = fmaxf(mloc[jr], tm);
                    float corr = __expf(mloc[jr] - mn);
                    mloc[jr] = mn; lloc[jr] *= corr;
                    od[0][jr] *= corr; od[1][jr] *= corr; od[2][jr] *= corr; od[3][jr] *= corr;
                }
                float ps = 0.f;
                #pragma unroll
                for (int nb = 0; nb < 4; ++nb) {
                    float p = __expf(s[nb] - mloc[jr]);
                    ps += p;
                    pls[w][r * 72 + nb * 16 + lr] = f2b(p);
                }
                lloc[jr] += ps;
            }

            #pragma unroll
            for (int ks = 0; ks < 2; ++ks) {
                bf16x8 pa = *(const bf16x8*)&pls[w][lr * 72 + ks * 32 + lg * 8];
                #pragma unroll
                for (int nb = 0; nb < 4; ++nb) {
                    int d = nb * 16 + lr;
                    bf16x8 vb = *(const bf16x8*)&vbuf[cur][d * 64 + (((4 * ks + lg) ^ (d & 7)) * 8)];
                    od[nb] = __builtin_amdgcn_mfma_f32_16x16x32_bf16(pa, vb, od[nb], 0, 0, 0);
                }
            }
            __syncthreads();
            cur ^= 1;
        }

        #pragma unroll
        for (int jr = 0; jr < 4; ++jr) {
            #pragma unroll
            for (int mk = 1; mk < 16; mk <<= 1) lloc[jr] += __shfl_xor(lloc[jr], mk);
            float inv = 1.f / lloc[jr];
            if (ph == 0) {
                #pragma unroll
                for (int nb = 0; nb < 4; ++nb) o0s[nb][jr] = od[nb][jr] * inv;
            } else {
                #pragma unroll
                for (int nb = 0; nb < 4; ++nb) {
                    float d = o0s[nb][jr] - od[nb][jr] * inv;
                    local += d * d;
                }
            }
        }
    }

    #pragma unroll
    for (int mk = 1; mk < 64; mk <<= 1) local += __shfl_xor(local, mk);
    if (lane == 0) red[w] = local;
    __syncthreads();
    if (tid == 0) atomicAdd(acc, red[0] + red[1] + red[2] + red[3]);
}

__global__ void finish_aux(const float* __restrict__ acc, float* __restrict__ out)
{
    out[0] = acc[0] * (1.0f / 4194304.0f);
}

// ---------------- launch ----------------
extern "C" void kernel_launch(void* const* d_in, const int* in_sizes, int n_in,
                              void* d_out, int out_size, void* d_ws, size_t ws_size,
                              hipStream_t stream)
{
    const float* x     = (const float*)d_in[0];
    const float* mem   = (const float*)d_in[1];
    const float* cmem  = (const float*)d_in[2];
    const float* pos   = (const float*)d_in[3];
    const float* Wq    = (const float*)d_in[5];
    const float* Wkv   = (const float*)d_in[6];
    const float* Wout  = (const float*)d_in[7];
    const float* bout  = (const float*)d_in[8];
    const float* convw = (const float*)d_in[9];
    const float* convb = (const float*)d_in[10];

    float* out      = (float*)d_out;
    float* logits   = out;
    float* new_mem  = out + 4194304;
    float* new_cmem = out + 8388608;
    float* aux_out  = out + 9437184;

    char* p = (char*)d_ws;
    u16* kvb   = (u16*)p; p += (size_t)9216 * 2048 * 2;
    u16* qb    = (u16*)p; p += (size_t)4096 * 1024 * 2;
    u16* kvin  = (u16*)p; p += (size_t)9216 * 1024 * 2;   // reused as vt after kv GEMM
    u16* wkvt  = (u16*)p; p += (size_t)2048 * 1024 * 2;
    u16* wqt   = (u16*)p; p += (size_t)1024 * 1024 * 2;
    u16* woutt = (u16*)p; p += (size_t)1024 * 1024 * 2;
    u16* w2t   = (u16*)p; p += (size_t)1024 * 4096 * 2;   // reused as cvt after compress GEMM
    u16* peb   = (u16*)p; p += (size_t)16 * 2304 * 64 * 2;
    u16* xb    = (u16*)p; p += (size_t)4096 * 1024 * 2;
    u16* memb  = (u16*)p; p += (size_t)4096 * 1024 * 2;
    u16* cmpb  = (u16*)p; p += (size_t)1024 * 1024 * 2;
    u16* ckcvb = (u16*)p; p += (size_t)1024 * 2048 * 2;
    u16* aob   = (u16*)p; p += (size_t)4096 * 1024 * 2;
    float* acc = (float*)p;
    u16* vt  = kvin;   // 4096 x 2304 = 9,437,184 u16, exact fit
    u16* cvt = w2t;    // 4096 x 256 needed, fits in 4M region

    hipMemcpyAsync(new_mem, x, (size_t)4194304 * sizeof(float),
                   hipMemcpyDeviceToDevice, stream);

    cvt_bf16<<<4096, 256, 0, stream>>>(x, xb, 1048576);
    cvt_bf16<<<4096, 256, 0, stream>>>(mem, memb, 1048576);
    cvt_bf16<<<2304, 256, 0, stream>>>(pos, peb, 589824);
    concat_bf16<<<9216, 256, 0, stream>>>(x, mem, cmem, kvin);
    transpose_bf16<<<dim3(64, 32), 256, 0, stream>>>(Wkv, wkvt, 1024, 2048);
    transpose_bf16<<<dim3(32, 32), 256, 0, stream>>>(Wq, wqt, 1024, 1024);
    transpose_bf16<<<dim3(32, 32), 256, 0, stream>>>(Wout, woutt, 1024, 1024);
    w2t_bf16<<<16384, 256, 0, stream>>>(convw, w2t);

    gemm_bf16<<<dim3(16, 72), 256, 0, stream>>>(kvin, wkvt, nullptr, nullptr, kvb, 9216, 2048, 1024);
    transpose_v<<<dim3(36, 64), 256, 0, stream>>>(kvb, 2304, vt);
    gemm_bf16<<<dim3(8, 32), 256, 0, stream>>>(xb, wqt, nullptr, nullptr, qb, 4096, 1024, 1024);
    gemm_bf16<<<dim3(8, 8), 256, 0, stream>>>(memb, w2t, convb, new_cmem, cmpb, 1024, 1024, 4096);
    gemm_bf16<<<dim3(16, 8), 256, 0, stream>>>(cmpb, wkvt, nullptr, nullptr, ckcvb, 1024, 2048, 1024);
    transpose_v<<<dim3(4, 64), 256, 0, stream>>>(ckcvb, 256, cvt);

    attn_main_mfma<<<dim3(16, 64), 256, 0, stream>>>(qb, kvb, vt, peb, aob);
    gemm_bf16<<<dim3(8, 32), 256, 0, stream>>>(aob, woutt, bout, logits, nullptr, 4096, 1024, 1024);

    hipMemsetAsync(acc, 0, sizeof(float), stream);
    attn_aux_mfma<<<dim3(16, 64), 256, 0, stream>>>(qb, kvb, vt, ckcvb, cvt, acc);
    finish_aux<<<1, 1, 0, stream>>>(acc, aux_out);
}

// Round 4
// 551.104 us; speedup vs baseline: 7.0585x; 1.0182x over previous
//
#include <hip/hip_runtime.h>
#include <hip/hip_bf16.h>
#include <cstddef>

typedef unsigned short u16;
typedef __attribute__((ext_vector_type(8))) short bf16x8;
typedef __attribute__((ext_vector_type(4))) float f32x4;

#define C2 0.18033688011112042f   // 0.125 * log2(e)

__device__ __forceinline__ u16 f2b(float f) {
    unsigned u = __builtin_bit_cast(unsigned, f);
    unsigned r = (u + 0x7FFF + ((u >> 16) & 1)) >> 16;
    return (u16)r;
}

__device__ __forceinline__ float exp2a(float x) {
    float r; asm("v_exp_f32 %0, %1" : "=v"(r) : "v"(x)); return r;
}

__device__ __forceinline__ unsigned cvtpk(float lo, float hi) {
    unsigned r; asm("v_cvt_pk_bf16_f32 %0, %1, %2" : "=v"(r) : "v"(lo), "v"(hi));
    return r;
}

__device__ __forceinline__ void gload_lds16(const void* g, void* l) {
    __builtin_amdgcn_global_load_lds(
        (const __attribute__((address_space(1))) unsigned int*)g,
        (__attribute__((address_space(3))) unsigned int*)l, 16, 0, 0);
}

// ---------------- elementwise fp32 -> bf16 ----------------
__global__ __launch_bounds__(256) void cvt_bf16(const float* __restrict__ in,
                                                u16* __restrict__ out, int n4)
{
    int i = blockIdx.x * 256 + threadIdx.x;
    if (i >= n4) return;
    float4 v = ((const float4*)in)[i];
    union { u16 s[4]; uint2 u; } pk;
    pk.s[0] = f2b(v.x); pk.s[1] = f2b(v.y); pk.s[2] = f2b(v.z); pk.s[3] = f2b(v.w);
    ((uint2*)out)[i] = pk.u;
}

// ---------------- kv_input concat (bf16) ----------------
__global__ __launch_bounds__(256) void concat_bf16(
    const float* __restrict__ x, const float* __restrict__ mem,
    const float* __restrict__ cmem, u16* __restrict__ out)
{
    int rowg = blockIdx.x;               // 0..9215
    int b = rowg / 2304, rr = rowg % 2304;
    const float* src = (rr < 256)  ? cmem + ((size_t)b * 256 + rr) * 1024
                     : (rr < 1280) ? mem  + ((size_t)b * 1024 + (rr - 256)) * 1024
                                   : x    + ((size_t)b * 1024 + (rr - 1280)) * 1024;
    float4 v = ((const float4*)src)[threadIdx.x];
    union { u16 s[4]; uint2 u; } pk;
    pk.s[0] = f2b(v.x); pk.s[1] = f2b(v.y); pk.s[2] = f2b(v.z); pk.s[3] = f2b(v.w);
    ((uint2*)(out + (size_t)rowg * 1024))[threadIdx.x] = pk.u;
}

// ---------------- transpose fp32 [K][N] -> bf16 [N][K] ----------------
__global__ __launch_bounds__(256) void transpose_bf16(
    const float* __restrict__ in, u16* __restrict__ out, int K, int N)
{
    __shared__ float t[32][33];
    int k0 = blockIdx.y * 32, n0 = blockIdx.x * 32;
    int tx = threadIdx.x & 31, ty = threadIdx.x >> 5;
    #pragma unroll
    for (int p = 0; p < 4; ++p)
        t[ty + 8 * p][tx] = in[(size_t)(k0 + ty + 8 * p) * N + n0 + tx];
    __syncthreads();
    #pragma unroll
    for (int p = 0; p < 4; ++p)
        out[(size_t)(n0 + ty + 8 * p) * K + k0 + tx] = f2b(t[tx][ty + 8 * p]);
}

// ---------------- conv_w[o,i,r] -> W2t[o][r*1024+i] bf16 ----------------
__global__ __launch_bounds__(256) void w2t_bf16(const float* __restrict__ cw,
                                                u16* __restrict__ out)
{
    size_t idx = (size_t)blockIdx.x * 256 + threadIdx.x;  // 1024*4096
    int o = (int)(idx >> 12), k = (int)(idx & 4095);
    out[idx] = f2b(cw[(size_t)o * 4096 + (k & 1023) * 4 + (k >> 10)]);
}

// ---------------- V half of [rows][2048] -> Vt[(bh*64+d)][rows] ----------------
__global__ __launch_bounds__(256) void transpose_v(
    const u16* __restrict__ src, int R, u16* __restrict__ dst)
{
    __shared__ u16 t[64 * 65];
    int bh = blockIdx.y, b = bh >> 4, h = bh & 15;
    int j0 = blockIdx.x * 64;
    int tid = threadIdx.x;
    #pragma unroll
    for (int p = 0; p < 2; ++p) {
        int idx = tid + p * 256;
        int j = idx >> 3, c = idx & 7;
        uint4 v = *(const uint4*)(src + ((size_t)(b * R + j0 + j)) * 2048 + 1024 + h * 64 + c * 8);
        const u16* vv = (const u16*)&v;
        #pragma unroll
        for (int u2 = 0; u2 < 8; ++u2) t[j * 65 + c * 8 + u2] = vv[u2];
    }
    __syncthreads();
    #pragma unroll
    for (int p = 0; p < 2; ++p) {
        int idx = tid + p * 256;
        int jc = idx & 7, d = idx >> 3;
        union { u16 s[8]; uint4 u; } pk;
        #pragma unroll
        for (int u2 = 0; u2 < 8; ++u2) pk.s[u2] = t[(jc * 8 + u2) * 65 + d];
        *(uint4*)(dst + ((size_t)(bh * 64 + d)) * (size_t)R + j0 + jc * 8) = pk.u;
    }
}

// ---------------- bf16 MFMA GEMM: C[M,N] = A[M,K] @ Bt[N,K]^T (+bias) ----------------
__global__ __launch_bounds__(256) void gemm_bf16(
    const u16* __restrict__ A, const u16* __restrict__ Bt,
    const float* __restrict__ bias, float* __restrict__ Cf,
    u16* __restrict__ Cb, int M, int N, int K)
{
    __shared__ u16 Al[128 * 32];
    __shared__ u16 Bl[128 * 32];
    const int tid = threadIdx.x, w = tid >> 6, lane = tid & 63;
    const int lr = lane & 15, lg = lane >> 4;
    const int bm0 = blockIdx.y * 128, bn0 = blockIdx.x * 128;
    const int wr = (w >> 1) * 64, wc = (w & 1) * 64;

    f32x4 acc[4][4];
    const f32x4 z = {0.f, 0.f, 0.f, 0.f};
    #pragma unroll
    for (int mb = 0; mb < 4; ++mb)
        #pragma unroll
        for (int nb = 0; nb < 4; ++nb) acc[mb][nb] = z;

    for (int k0 = 0; k0 < K; k0 += 32) {
        __syncthreads();
        #pragma unroll
        for (int q = 0; q < 2; ++q) {
            int chunk = w * 2 + q;
            int row = chunk * 16 + (lane >> 2);
            int sg = (lane & 3) * 8;
            gload_lds16(A + (size_t)(bm0 + row) * K + k0 + sg, &Al[chunk * 512]);
            gload_lds16(Bt + (size_t)(bn0 + row) * K + k0 + sg, &Bl[chunk * 512]);
        }
        __syncthreads();
        bf16x8 af[4], bf[4];
        #pragma unroll
        for (int mb = 0; mb < 4; ++mb)
            af[mb] = *(const bf16x8*)&Al[(wr + mb * 16 + lr) * 32 + lg * 8];
        #pragma unroll
        for (int nb = 0; nb < 4; ++nb)
            bf[nb] = *(const bf16x8*)&Bl[(wc + nb * 16 + lr) * 32 + lg * 8];
        #pragma unroll
        for (int mb = 0; mb < 4; ++mb)
            #pragma unroll
            for (int nb = 0; nb < 4; ++nb)
                acc[mb][nb] = __builtin_amdgcn_mfma_f32_16x16x32_bf16(
                    af[mb], bf[nb], acc[mb][nb], 0, 0, 0);
    }

    #pragma unroll
    for (int mb = 0; mb < 4; ++mb)
        #pragma unroll
        for (int nb = 0; nb < 4; ++nb)
            #pragma unroll
            for (int jr = 0; jr < 4; ++jr) {
                int row = bm0 + wr + mb * 16 + lg * 4 + jr;
                int col = bn0 + wc + nb * 16 + lr;
                float v = acc[mb][nb][jr] + (bias ? bias[col] : 0.f);
                if (Cf) Cf[(size_t)row * N + col] = v;
                if (Cb) Cb[(size_t)row * N + col] = f2b(v);
            }
}

// ---------------- fused main attention + aux phase-0 ----------------
__global__ __launch_bounds__(256) void attn_main_fused(
    const u16* __restrict__ qb,    // (4,1024,1024) bf16
    const u16* __restrict__ kvb,   // (4,2304,2048) bf16 k|v
    const u16* __restrict__ vt,    // (64bh*64d, 2304) bf16  V^T
    const u16* __restrict__ peb,   // (16,2304,64) bf16
    u16* __restrict__ outb,        // (4,1024,1024) bf16
    float* __restrict__ auxo)      // (64bh,1024,64) fp32 aux phase-0 out
{
    __shared__ u16 kbuf[2][64 * 64];
    __shared__ u16 vbuf[2][64 * 64];   // [d][j-chunks] swizzled
    __shared__ u16 pering[128 * 64];
    __shared__ u16 pls[4][16 * 72];    // reused: main P, then aux P (within-wave)
    __shared__ float qpls[4][16 * 83];

    const int tid = threadIdx.x;
    const int w = tid >> 6, lane = tid & 63;
    const int lr = lane & 15, lg = lane >> 4;
    const int rl = lane >> 3, cch = lane & 7;
    const int bh = blockIdx.y, b = bh >> 4, h = bh & 15;
    const int i0 = blockIdx.x * 64;
    const int iw = i0 + 16 * w;
    const int jb0 = 960 - i0;

    bf16x8 qf[2];
    #pragma unroll
    for (int ks = 0; ks < 2; ++ks)
        qf[ks] = *(const bf16x8*)(qb + ((size_t)(b * 1024 + iw + lr)) * 1024
                                  + h * 64 + ks * 32 + lg * 8);

    const f32x4 z = {0.f, 0.f, 0.f, 0.f};
    f32x4 od[4], od2[4];
    float mloc[4], lloc[4], ml2[4], ll2[4];
    #pragma unroll
    for (int nb = 0; nb < 4; ++nb) { od[nb] = z; od2[nb] = z; }
    #pragma unroll
    for (int jr = 0; jr < 4; ++jr) {
        mloc[jr] = -1e30f; lloc[jr] = 0.f;
        ml2[jr] = -1e30f; ll2[jr] = 0.f;
    }

    // ---- prologue: tile 0 K/V + full 128-row PE band ----
    #pragma unroll
    for (int q = 0; q < 2; ++q) {
        int row = 16 * w + 8 * q + rl;
        gload_lds16(kvb + ((size_t)(b * 2304 + row)) * 2048 + h * 64 + ((cch ^ rl) * 8),
                    &kbuf[0][(16 * w + 8 * q) * 64]);
        gload_lds16(vt + ((size_t)(bh * 64 + row)) * 2304 + ((cch ^ rl) * 8),
                    &vbuf[0][(16 * w + 8 * q) * 64]);
    }
    #pragma unroll
    for (int q = 0; q < 4; ++q) {
        int a = jb0 + 32 * w + 8 * q + rl;
        int srow = a > 2303 ? 2303 : a;
        gload_lds16(peb + ((size_t)(h * 2304 + srow)) * 64 + ((cch ^ rl) * 8),
                    &pering[((jb0 + 32 * w + 8 * q) & 127) * 64]);
    }
    __syncthreads();

    int cur = 0;
    const int nt = ((i0 + 1343) >> 6) + 1;
    for (int t = 0; t < nt; ++t) {
        const int j0 = t * 64;
        const int jb = jb0 + j0;
        const bool more = (t + 1 < nt);

        if (more) {   // K/V staging for next tile
            const int j0n = j0 + 64;
            #pragma unroll
            for (int q = 0; q < 2; ++q) {
                int row = 16 * w + 8 * q + rl;
                gload_lds16(kvb + ((size_t)(b * 2304 + j0n + row)) * 2048 + h * 64 + ((cch ^ rl) * 8),
                            &kbuf[cur ^ 1][(16 * w + 8 * q) * 64]);
                gload_lds16(vt + ((size_t)(bh * 64 + row)) * 2304 + j0n + ((cch ^ rl) * 8),
                            &vbuf[cur ^ 1][(16 * w + 8 * q) * 64]);
            }
        }

        // ---- QK & QP MFMA ----
        f32x4 qk[4], qp[5];
        #pragma unroll
        for (int nb = 0; nb < 4; ++nb) qk[nb] = z;
        #pragma unroll
        for (int f = 0; f < 5; ++f) qp[f] = z;
        #pragma unroll
        for (int ks = 0; ks < 2; ++ks) {
            #pragma unroll
            for (int nb = 0; nb < 4; ++nb) {
                int row = nb * 16 + lr;
                bf16x8 kb = *(const bf16x8*)&kbuf[cur][row * 64 + (((4 * ks + lg) ^ (row & 7)) * 8)];
                qk[nb] = __builtin_amdgcn_mfma_f32_16x16x32_bf16(qf[ks], kb, qk[nb], 0, 0, 0);
            }
            #pragma unroll
            for (int f = 0; f < 5; ++f) {
                int rel = 48 - 16 * w + f * 16 + lr;
                int slot = (jb + rel) & 127;
                bf16x8 pb = *(const bf16x8*)&pering[slot * 64 + (((4 * ks + lg) ^ (slot & 7)) * 8)];
                qp[f] = __builtin_amdgcn_mfma_f32_16x16x32_bf16(qf[ks], pb, qp[f], 0, 0, 0);
            }
        }

        __builtin_amdgcn_s_barrier();   // raw: all waves' PE reads complete

        if (more) {   // PE ring: stage the 64 new rows for next tile
            const int A0 = jb + 128;
            #pragma unroll
            for (int q = 0; q < 2; ++q) {
                int a = A0 + 16 * w + 8 * q + rl;
                int srow = a > 2303 ? 2303 : a;
                gload_lds16(peb + ((size_t)(h * 2304 + srow)) * 64 + ((cch ^ rl) * 8),
                            &pering[((A0 + 16 * w + 8 * q) & 127) * 64]);
            }
        }

        // ---- spill qp to LDS for diagonal gather ----
        #pragma unroll
        for (int f = 0; f < 5; ++f)
            #pragma unroll
            for (int jr = 0; jr < 4; ++jr)
                qpls[w][(lg * 4 + jr) * 83 + f * 16 + lr] = qp[f][jr];

        // ---- main: mask + defer-max online softmax (log2 domain) ----
        const bool nomask = (j0 + 63 <= iw + 1280);
        #pragma unroll
        for (int jr = 0; jr < 4; ++jr) {
            const int r = lg * 4 + jr;
            const int ia = iw + r;
            float s0 = (qk[0][jr] + qpls[w][r * 82 + lr + 15]) * C2;
            float s1 = (qk[1][jr] + qpls[w][r * 82 + lr + 31]) * C2;
            float s2 = (qk[2][jr] + qpls[w][r * 82 + lr + 47]) * C2;
            float s3 = (qk[3][jr] + qpls[w][r * 82 + lr + 63]) * C2;
            if (!nomask) {
                s0 = (j0 + lr      <= ia + 1280) ? s0 : -1e30f;
                s1 = (j0 + lr + 16 <= ia + 1280) ? s1 : -1e30f;
                s2 = (j0 + lr + 32 <= ia + 1280) ? s2 : -1e30f;
                s3 = (j0 + lr + 48 <= ia + 1280) ? s3 : -1e30f;
            }
            float lm = fmaxf(fmaxf(s0, s1), fmaxf(s2, s3));
            if (__any(lm > mloc[jr] + 11.f)) {
                float tm = lm;
                #pragma unroll
                for (int mk = 1; mk < 16; mk <<= 1) tm = fmaxf(tm, __shfl_xor(tm, mk));
                float mn = fmaxf(mloc[jr], tm);
                float corr = exp2a(mloc[jr] - mn);
                mloc[jr] = mn; lloc[jr] *= corr;
                od[0][jr] *= corr; od[1][jr] *= corr; od[2][jr] *= corr; od[3][jr] *= corr;
            }
            float p0 = exp2a(s0 - mloc[jr]), p1 = exp2a(s1 - mloc[jr]);
            float p2 = exp2a(s2 - mloc[jr]), p3 = exp2a(s3 - mloc[jr]);
            unsigned pkA = cvtpk(p0, p1), pkB = cvtpk(p2, p3);
            pls[w][r * 72 + lr]      = (u16)pkA;
            pls[w][r * 72 + 16 + lr] = (u16)(pkA >> 16);
            pls[w][r * 72 + 32 + lr] = (u16)pkB;
            pls[w][r * 72 + 48 + lr] = (u16)(pkB >> 16);
            lloc[jr] += (p0 + p1) + (p2 + p3);
        }

        // ---- main PV MFMA ----
        #pragma unroll
        for (int ks = 0; ks < 2; ++ks) {
            bf16x8 pa = *(const bf16x8*)&pls[w][lr * 72 + ks * 32 + lg * 8];
            #pragma unroll
            for (int nb = 0; nb < 4; ++nb) {
                int d = nb * 16 + lr;
                bf16x8 vb = *(const bf16x8*)&vbuf[cur][d * 64 + (((4 * ks + lg) ^ (d & 7)) * 8)];
                od[nb] = __builtin_amdgcn_mfma_f32_16x16x32_bf16(pa, vb, od[nb], 0, 0, 0);
            }
        }

        // ---- aux phase-0: kv rows 256..1279 == tiles 4..19 (no pos, no mask) ----
        if (t >= 4 && t <= 19) {
            #pragma unroll
            for (int jr = 0; jr < 4; ++jr) {
                const int r = lg * 4 + jr;
                float s0 = qk[0][jr] * C2, s1 = qk[1][jr] * C2;
                float s2 = qk[2][jr] * C2, s3 = qk[3][jr] * C2;
                float lm = fmaxf(fmaxf(s0, s1), fmaxf(s2, s3));
                if (__any(lm > ml2[jr] + 11.f)) {
                    float tm = lm;
                    #pragma unroll
                    for (int mk = 1; mk < 16; mk <<= 1) tm = fmaxf(tm, __shfl_xor(tm, mk));
                    float mn = fmaxf(ml2[jr], tm);
                    float corr = exp2a(ml2[jr] - mn);
                    ml2[jr] = mn; ll2[jr] *= corr;
                    od2[0][jr] *= corr; od2[1][jr] *= corr; od2[2][jr] *= corr; od2[3][jr] *= corr;
                }
                float p0 = exp2a(s0 - ml2[jr]), p1 = exp2a(s1 - ml2[jr]);
                float p2 = exp2a(s2 - ml2[jr]), p3 = exp2a(s3 - ml2[jr]);
                unsigned pkA = cvtpk(p0, p1), pkB = cvtpk(p2, p3);
                pls[w][r * 72 + lr]      = (u16)pkA;
                pls[w][r * 72 + 16 + lr] = (u16)(pkA >> 16);
                pls[w][r * 72 + 32 + lr] = (u16)pkB;
                pls[w][r * 72 + 48 + lr] = (u16)(pkB >> 16);
                ll2[jr] += (p0 + p1) + (p2 + p3);
            }
            #pragma unroll
            for (int ks = 0; ks < 2; ++ks) {
                bf16x8 pa = *(const bf16x8*)&pls[w][lr * 72 + ks * 32 + lg * 8];
                #pragma unroll
                for (int nb = 0; nb < 4; ++nb) {
                    int d = nb * 16 + lr;
                    bf16x8 vb = *(const bf16x8*)&vbuf[cur][d * 64 + (((4 * ks + lg) ^ (d & 7)) * 8)];
                    od2[nb] = __builtin_amdgcn_mfma_f32_16x16x32_bf16(pa, vb, od2[nb], 0, 0, 0);
                }
            }
        }

        __syncthreads();   // drains staging vmem + all LDS reads
        cur ^= 1;
    }

    // ---- main epilogue ----
    #pragma unroll
    for (int jr = 0; jr < 4; ++jr) {
        float l = lloc[jr];
        #pragma unroll
        for (int mk = 1; mk < 16; mk <<= 1) l += __shfl_xor(l, mk);
        float inv = 1.f / l;
        int ia = iw + lg * 4 + jr;
        #pragma unroll
        for (int nb = 0; nb < 4; ++nb)
            outb[((size_t)(b * 1024 + ia)) * 1024 + h * 64 + nb * 16 + lr] =
                f2b(od[nb][jr] * inv);
    }
    // ---- aux phase-0 epilogue ----
    #pragma unroll
    for (int jr = 0; jr < 4; ++jr) {
        float l = ll2[jr];
        #pragma unroll
        for (int mk = 1; mk < 16; mk <<= 1) l += __shfl_xor(l, mk);
        float inv = 1.f / l;
        int ig = i0 + 16 * w + lg * 4 + jr;
        #pragma unroll
        for (int nb = 0; nb < 4; ++nb)
            auxo[((size_t)(bh * 1024 + ig)) * 64 + nb * 16 + lr] = od2[nb][jr] * inv;
    }
}

// ---------------- aux phase-1 (compressed KV) + squared diff ----------------
__global__ __launch_bounds__(256) void attn_aux_diff(
    const u16* __restrict__ qb, const u16* __restrict__ ckcv,
    const u16* __restrict__ cvt, const float* __restrict__ auxo,
    float* __restrict__ acc)
{
    __shared__ u16 kbuf[64 * 64];
    __shared__ u16 vbuf[64 * 64];
    __shared__ u16 pls[4][16 * 72];
    __shared__ float red[4];

    const int tid = threadIdx.x;
    const int w = tid >> 6, lane = tid & 63;
    const int lr = lane & 15, lg = lane >> 4;
    const int rl = lane >> 3, cch = lane & 7;
    const int bh = blockIdx.y, b = bh >> 4, h = bh & 15;
    const int i0 = blockIdx.x * 64;
    const int iw = i0 + 16 * w;

    const u16* kbase = ckcv + ((size_t)(b * 256)) * 2048 + h * 64;
    const u16* vbase = cvt + ((size_t)(bh * 64)) * 256;

    bf16x8 qf[2];
    #pragma unroll
    for (int ks = 0; ks < 2; ++ks)
        qf[ks] = *(const bf16x8*)(qb + ((size_t)(b * 1024 + iw + lr)) * 1024
                                  + h * 64 + ks * 32 + lg * 8);

    const f32x4 z = {0.f, 0.f, 0.f, 0.f};
    f32x4 od[4];
    float mloc[4], lloc[4];
    #pragma unroll
    for (int nb = 0; nb < 4; ++nb) od[nb] = z;
    #pragma unroll
    for (int jr = 0; jr < 4; ++jr) { mloc[jr] = -1e30f; lloc[jr] = 0.f; }

    for (int t = 0; t < 4; ++t) {
        const int j0 = t * 64;
        __syncthreads();
        #pragma unroll
        for (int q = 0; q < 2; ++q) {
            int row = 16 * w + 8 * q + rl;
            gload_lds16(kbase + (size_t)(j0 + row) * 2048 + ((cch ^ rl) * 8),
                        &kbuf[(16 * w + 8 * q) * 64]);
            gload_lds16(vbase + (size_t)row * 256 + j0 + ((cch ^ rl) * 8),
                        &vbuf[(16 * w + 8 * q) * 64]);
        }
        __syncthreads();

        f32x4 qk[4];
        #pragma unroll
        for (int nb = 0; nb < 4; ++nb) qk[nb] = z;
        #pragma unroll
        for (int ks = 0; ks < 2; ++ks)
            #pragma unroll
            for (int nb = 0; nb < 4; ++nb) {
                int row = nb * 16 + lr;
                bf16x8 kb = *(const bf16x8*)&kbuf[row * 64 + (((4 * ks + lg) ^ (row & 7)) * 8)];
                qk[nb] = __builtin_amdgcn_mfma_f32_16x16x32_bf16(qf[ks], kb, qk[nb], 0, 0, 0);
            }

        #pragma unroll
        for (int jr = 0; jr < 4; ++jr) {
            const int r = lg * 4 + jr;
            float s0 = qk[0][jr] * C2, s1 = qk[1][jr] * C2;
            float s2 = qk[2][jr] * C2, s3 = qk[3][jr] * C2;
            float lm = fmaxf(fmaxf(s0, s1), fmaxf(s2, s3));
            if (__any(lm > mloc[jr] + 11.f)) {
                float tm = lm;
                #pragma unroll
                for (int mk = 1; mk < 16; mk <<= 1) tm = fmaxf(tm, __shfl_xor(tm, mk));
                float mn = fmaxf(mloc[jr], tm);
                float corr = exp2a(mloc[jr] - mn);
                mloc[jr] = mn; lloc[jr] *= corr;
                od[0][jr] *= corr; od[1][jr] *= corr; od[2][jr] *= corr; od[3][jr] *= corr;
            }
            float p0 = exp2a(s0 - mloc[jr]), p1 = exp2a(s1 - mloc[jr]);
            float p2 = exp2a(s2 - mloc[jr]), p3 = exp2a(s3 - mloc[jr]);
            unsigned pkA = cvtpk(p0, p1), pkB = cvtpk(p2, p3);
            pls[w][r * 72 + lr]      = (u16)pkA;
            pls[w][r * 72 + 16 + lr] = (u16)(pkA >> 16);
            pls[w][r * 72 + 32 + lr] = (u16)pkB;
            pls[w][r * 72 + 48 + lr] = (u16)(pkB >> 16);
            lloc[jr] += (p0 + p1) + (p2 + p3);
        }

        #pragma unroll
        for (int ks = 0; ks < 2; ++ks) {
            bf16x8 pa = *(const bf16x8*)&pls[w][lr * 72 + ks * 32 + lg * 8];
            #pragma unroll
            for (int nb = 0; nb < 4; ++nb) {
                int d = nb * 16 + lr;
                bf16x8 vb = *(const bf16x8*)&vbuf[d * 64 + (((4 * ks + lg) ^ (d & 7)) * 8)];
                od[nb] = __builtin_amdgcn_mfma_f32_16x16x32_bf16(pa, vb, od[nb], 0, 0, 0);
            }
        }
    }

    float local = 0.f;
    #pragma unroll
    for (int jr = 0; jr < 4; ++jr) {
        float l = lloc[jr];
        #pragma unroll
        for (int mk = 1; mk < 16; mk <<= 1) l += __shfl_xor(l, mk);
        float inv = 1.f / l;
        int ig = i0 + 16 * w + lg * 4 + jr;
        #pragma unroll
        for (int nb = 0; nb < 4; ++nb) {
            float o2 = od[nb][jr] * inv;
            float o1 = auxo[((size_t)(bh * 1024 + ig)) * 64 + nb * 16 + lr];
            float d = o1 - o2;
            local += d * d;
        }
    }
    #pragma unroll
    for (int mk = 1; mk < 64; mk <<= 1) local += __shfl_xor(local, mk);
    if (lane == 0) red[w] = local;
    __syncthreads();
    if (tid == 0) atomicAdd(acc, red[0] + red[1] + red[2] + red[3]);
}

__global__ void finish_aux(const float* __restrict__ acc, float* __restrict__ out)
{
    out[0] = acc[0] * (1.0f / 4194304.0f);
}

// ---------------- launch ----------------
extern "C" void kernel_launch(void* const* d_in, const int* in_sizes, int n_in,
                              void* d_out, int out_size, void* d_ws, size_t ws_size,
                              hipStream_t stream)
{
    const float* x     = (const float*)d_in[0];
    const float* mem   = (const float*)d_in[1];
    const float* cmem  = (const float*)d_in[2];
    const float* pos   = (const float*)d_in[3];
    const float* Wq    = (const float*)d_in[5];
    const float* Wkv   = (const float*)d_in[6];
    const float* Wout  = (const float*)d_in[7];
    const float* bout  = (const float*)d_in[8];
    const float* convw = (const float*)d_in[9];
    const float* convb = (const float*)d_in[10];

    float* out      = (float*)d_out;
    float* logits   = out;
    float* new_mem  = out + 4194304;
    float* new_cmem = out + 8388608;
    float* aux_out  = out + 9437184;

    char* p = (char*)d_ws;
    u16* kvb   = (u16*)p; p += (size_t)9216 * 2048 * 2;
    u16* qb    = (u16*)p; p += (size_t)4096 * 1024 * 2;
    u16* kvin  = (u16*)p; p += (size_t)9216 * 1024 * 2;   // reused as vt after kv GEMM
    u16* wkvt  = (u16*)p; p += (size_t)2048 * 1024 * 2;
    u16* wqt   = (u16*)p; p += (size_t)1024 * 1024 * 2;
    u16* woutt = (u16*)p; p += (size_t)1024 * 1024 * 2;
    u16* w2t   = (u16*)p; p += (size_t)1024 * 4096 * 2;   // reused as cvt after compress GEMM
    u16* peb   = (u16*)p; p += (size_t)16 * 2304 * 64 * 2;
    u16* xb    = (u16*)p; p += (size_t)4096 * 1024 * 2;   // reused (with memb) as auxo
    u16* memb  = (u16*)p; p += (size_t)4096 * 1024 * 2;
    u16* cmpb  = (u16*)p; p += (size_t)1024 * 1024 * 2;
    u16* ckcvb = (u16*)p; p += (size_t)1024 * 2048 * 2;
    u16* aob   = (u16*)p; p += (size_t)4096 * 1024 * 2;
    float* acc = (float*)p;
    u16* vt   = kvin;          // 4096 x 2304 u16, exact fit
    u16* cvt  = w2t;           // 4096 x 256 u16, fits
    float* auxo = (float*)xb;  // 4,194,304 f32 == xb+memb region exactly

    hipMemcpyAsync(new_mem, x, (size_t)4194304 * sizeof(float),
                   hipMemcpyDeviceToDevice, stream);

    cvt_bf16<<<4096, 256, 0, stream>>>(x, xb, 1048576);
    cvt_bf16<<<4096, 256, 0, stream>>>(mem, memb, 1048576);
    cvt_bf16<<<2304, 256, 0, stream>>>(pos, peb, 589824);
    concat_bf16<<<9216, 256, 0, stream>>>(x, mem, cmem, kvin);
    transpose_bf16<<<dim3(64, 32), 256, 0, stream>>>(Wkv, wkvt, 1024, 2048);
    transpose_bf16<<<dim3(32, 32), 256, 0, stream>>>(Wq, wqt, 1024, 1024);
    transpose_bf16<<<dim3(32, 32), 256, 0, stream>>>(Wout, woutt, 1024, 1024);
    w2t_bf16<<<16384, 256, 0, stream>>>(convw, w2t);

    gemm_bf16<<<dim3(16, 72), 256, 0, stream>>>(kvin, wkvt, nullptr, nullptr, kvb, 9216, 2048, 1024);
    transpose_v<<<dim3(36, 64), 256, 0, stream>>>(kvb, 2304, vt);
    gemm_bf16<<<dim3(8, 32), 256, 0, stream>>>(xb, wqt, nullptr, nullptr, qb, 4096, 1024, 1024);
    gemm_bf16<<<dim3(8, 8), 256, 0, stream>>>(memb, w2t, convb, new_cmem, cmpb, 1024, 1024, 4096);
    gemm_bf16<<<dim3(16, 8), 256, 0, stream>>>(cmpb, wkvt, nullptr, nullptr, ckcvb, 1024, 2048, 1024);
    transpose_v<<<dim3(4, 64), 256, 0, stream>>>(ckcvb, 256, cvt);

    // xb/memb dead from here -> auxo overlays them
    attn_main_fused<<<dim3(16, 64), 256, 0, stream>>>(qb, kvb, vt, peb, aob, auxo);
    gemm_bf16<<<dim3(8, 32), 256, 0, stream>>>(aob, woutt, bout, logits, nullptr, 4096, 1024, 1024);

    hipMemsetAsync(acc, 0, sizeof(float), stream);
    attn_aux_diff<<<dim3(16, 64), 256, 0, stream>>>(qb, ckcvb, cvt, auxo, acc);
    finish_aux<<<1, 1, 0, stream>>>(acc, aux_out);
}